// Round 18
// baseline (281.463 us; speedup 1.0000x reference)
//
#include <hip/hip_runtime.h>
#include <cstddef>

// Problem constants: S=8, B=32, D=5, T=30, E=768, H=128, 4H=512.

typedef __attribute__((ext_vector_type(8))) _Float16 f16x8;
typedef __attribute__((ext_vector_type(4))) _Float16 f16x4;
typedef __attribute__((ext_vector_type(2))) _Float16 f16x2;
typedef __attribute__((ext_vector_type(4))) float f32x4;

__device__ __forceinline__ float rcp_(float x) { return __builtin_amdgcn_rcpf(x); }
__device__ __forceinline__ float sigf(float x) { return rcp_(1.0f + __expf(-x)); }
__device__ __forceinline__ float tanhf_(float x) { return 1.0f - 2.0f * rcp_(__expf(2.0f * x) + 1.0f); }

// LDS-only barrier: drains lgkmcnt but NOT vmcnt (global ops stay in flight).
__device__ __forceinline__ void barrier_lds_only() {
  asm volatile("s_waitcnt lgkmcnt(0)" ::: "memory");
  __builtin_amdgcn_s_barrier();
  __builtin_amdgcn_sched_barrier(0);
}

// ---------------------------------------------------------------------------
// K0r: per-stock compacted row map: rows (n,t) with t < len[s,n].
// ---------------------------------------------------------------------------
__global__ __launch_bounds__(256) void k0_rowmap(const int* __restrict__ lens,
                                                 int* __restrict__ rowmap,
                                                 int* __restrict__ Ms) {
  const int s = blockIdx.x;
  const int tid = threadIdx.x;
  __shared__ int st[160];
  __shared__ int ln[160];
  if (tid < 160) {
    const int b = tid / 5, d = tid % 5;
    ln[tid] = lens[(b * 8 + s) * 5 + d];
  }
  __syncthreads();
  if (tid == 0) {
    int run = 0;
    for (int n = 0; n < 160; ++n) { st[n] = run; run += ln[n]; }
    Ms[s] = run;
  }
  __syncthreads();
  if (tid < 160) {
    const int base = st[tid], l = ln[tid];
    for (int t = 0; t < l; ++t) rowmap[s * 4800 + base + t] = tid * 30 + t;
  }
}

// ---------------------------------------------------------------------------
// K0: transpose U to fp16 (hi only) via LDS tiles (for k1).
// ---------------------------------------------------------------------------
__global__ __launch_bounds__(256) void k0_usplit(const float* __restrict__ U,
                                                 _Float16* __restrict__ Uh) {
  const int s = blockIdx.z;
  const int k0 = blockIdx.x * 64;
  const int n0 = blockIdx.y * 64;
  const int tid = threadIdx.x;
  __shared__ _Float16 Th[64 * 66];
  const float* Us = U + (size_t)s * 768 * 512;
#pragma unroll
  for (int rep = 0; rep < 16; ++rep) {
    const int idx = rep * 256 + tid;
    const int r = idx >> 6, c = idx & 63;
    Th[r * 66 + c] = (_Float16)Us[(size_t)(k0 + r) * 512 + n0 + c];
  }
  __syncthreads();
  _Float16* uhs = Uh + (size_t)s * 512 * 768;
#pragma unroll
  for (int rep = 0; rep < 8; ++rep) {
    const int idx = rep * 256 + tid;
    const int nn = idx >> 5;
    const int kp = (idx & 31) * 2;
    const f16x2 h2 = {Th[kp * 66 + nn], Th[(kp + 1) * 66 + nn]};
    *(f16x2*)&uhs[(size_t)(n0 + nn) * 768 + k0 + kp] = h2;
  }
}

// ---------------------------------------------------------------------------
// K0w: pack Wall (hi only) and Wd (hi) into MFMA B-fragment-linear layout.
// ---------------------------------------------------------------------------
__global__ __launch_bounds__(256) void k0_wprep(const float* __restrict__ Wall,
                                                const float* __restrict__ Wd,
                                                _Float16* __restrict__ Wfh,
                                                _Float16* __restrict__ Dfh) {
  const int w = blockIdx.x, s = blockIdx.y;
  const int tid = threadIdx.x;
  const float* Ws = Wall + (size_t)s * 65536;
  _Float16* oh = Wfh + (size_t)(s * 8 + w) * 8192;
  for (int c = tid; c < 1024; c += 256) {
    const int kt = c >> 8, nt = (c >> 6) & 3, l = c & 63;
    const int n = nt * 128 + w * 16 + (l & 15);   // gate-major per wave
    const int kb = kt * 32 + ((l >> 4) << 3);
    f16x8 hv;
#pragma unroll
    for (int e = 0; e < 8; ++e) hv[e] = (_Float16)Ws[(size_t)(kb + e) * 512 + n];
    *(f16x8*)&oh[c * 8] = hv;
  }
  {
    const float* Ds = Wd + (size_t)s * 16384;
    _Float16* od = Dfh + (size_t)(s * 8 + w) * 2048;
    const int c = tid;
    const int kt = c >> 6, l = c & 63;
    const int n = w * 16 + (l & 15);
    const int kb = kt * 32 + ((l >> 4) << 3);
    f16x8 hv;
#pragma unroll
    for (int e = 0; e < 8; ++e) hv[e] = (_Float16)Ds[(size_t)(kb + e) * 128 + n];
    *(f16x8*)&od[c * 8] = hv;
  }
}

// ---------------------------------------------------------------------------
// K0a: pack a1_W1 and a1_W2 into per-wave 16-col B-frag layout.
// ---------------------------------------------------------------------------
__global__ __launch_bounds__(256) void k0_aprep(const float* __restrict__ W1,
                                                const float* __restrict__ W2,
                                                _Float16* __restrict__ W1f,
                                                _Float16* __restrict__ W2f) {
  const int w = blockIdx.x, s = blockIdx.y;
  const int c = threadIdx.x;          // 0..255 = kt*64 + l
  const int kt = c >> 6, l = c & 63;
  const int n = w * 16 + (l & 15);
  const int kb = kt * 32 + ((l >> 4) << 3);
  const float* W1s = W1 + (size_t)s * 16384;
  const float* W2s = W2 + (size_t)s * 16384;
  f16x8 v1, v2;
#pragma unroll
  for (int e = 0; e < 8; ++e) {
    v1[e] = (_Float16)W1s[(size_t)(kb + e) * 128 + n];
    v2[e] = (_Float16)W2s[(size_t)(kb + e) * 128 + n];
  }
  *(f16x8*)&W1f[(size_t)(s * 8 + w) * 2048 + c * 8] = v1;
  *(f16x8*)&W2f[(size_t)(s * 8 + w) * 2048 + c * 8] = v2;
}

// ---------------------------------------------------------------------------
// K1 v6: prefetch distance 2. Loads for step ks+2 issue at iteration ks
//   (one full step of latency cover); the stage-write's vmcnt wait keeps the
//   newer set in flight. Named register sets (A/B), manual 2x unroll.
// ---------------------------------------------------------------------------
__global__ __launch_bounds__(256, 4) void k1_xu(const float* __restrict__ sent,
                                                const _Float16* __restrict__ Uh,
                                                const float* __restrict__ bU,
                                                const int* __restrict__ rowmap,
                                                const int* __restrict__ Ms,
                                                float* __restrict__ XU) {
  const int s = blockIdx.x;
  const int M = Ms[s];
  const int nt = blockIdx.y & 3;
  const int mt = blockIdx.y >> 2;
  if (mt * 128 >= M) return;
  const int tid = threadIdx.x;
  const int lane = tid & 63, wid = tid >> 6;
  const int wm = wid >> 1, wn = wid & 1;

  __shared__ _Float16 Al[2][128 * 32];
  __shared__ _Float16 Bh[2][128 * 32];

  const int ar1 = tid >> 2;
  const int chk = tid & 3;
  const int afk = chk * 8;
  const int fw = (ar1 ^ (ar1 >> 2)) & 3;
  const int wA1 = ar1 * 32 + ((chk ^ fw) * 8);
  const int wA2 = wA1 + 64 * 32;

  const int* rms = rowmap + s * 4800;
  const float* asrc1;
  const float* asrc2;
  {
    int i1 = mt * 128 + ar1; if (i1 > M - 1) i1 = M - 1;
    const int grow = rms[i1];
    const int nn = grow / 30, tt = grow % 30, ab = nn / 5, ad = nn % 5;
    asrc1 = sent + (size_t)((((ab * 8 + s) * 5 + ad) * 30) + tt) * 768 + afk;
  }
  {
    int i2 = mt * 128 + ar1 + 64; if (i2 > M - 1) i2 = M - 1;
    const int grow = rms[i2];
    const int nn = grow / 30, tt = grow % 30, ab = nn / 5, ad = nn % 5;
    asrc2 = sent + (size_t)((((ab * 8 + s) * 5 + ad) * 30) + tt) * 768 + afk;
  }
  const _Float16* UhS = Uh + (size_t)s * 512 * 768;
  const _Float16* bh1 = UhS + (size_t)(nt * 128 + ar1) * 768 + afk;
  const _Float16* bh2 = UhS + (size_t)(nt * 128 + ar1 + 64) * 768 + afk;

  const int q = lane >> 4;
  const int l15 = lane & 15;
  int aoff[4], boff[4];
#pragma unroll
  for (int f = 0; f < 4; ++f) {
    {
      const int row = wm * 64 + f * 16 + l15;
      const int fr = (row ^ (row >> 2)) & 3;
      aoff[f] = row * 32 + ((q ^ fr) * 8);
    }
    {
      const int row = wn * 64 + f * 16 + l15;
      const int fr = (row ^ (row >> 2)) & 3;
      boff[f] = row * 32 + ((q ^ fr) * 8);
    }
  }

  f32x4 acc[4][4];
#pragma unroll
  for (int i = 0; i < 4; ++i)
#pragma unroll
    for (int j = 0; j < 4; ++j) acc[i][j] = (f32x4){0.f, 0.f, 0.f, 0.f};

  // two named prefetch register sets
  float4 Aa1a, Aa1b, Aa2a, Aa2b; f16x8 Avh1, Avh2;   // set A
  float4 Ba1a, Ba1b, Ba2a, Ba2b; f16x8 Bvh1, Bvh2;   // set B

#define K1_LOAD(SET, KO) \
  SET##a1a = *(const float4*)(asrc1 + (KO)); \
  SET##a1b = *(const float4*)(asrc1 + (KO) + 4); \
  SET##a2a = *(const float4*)(asrc2 + (KO)); \
  SET##a2b = *(const float4*)(asrc2 + (KO) + 4); \
  SET##vh1 = *(const f16x8*)(bh1 + (KO)); \
  SET##vh2 = *(const f16x8*)(bh2 + (KO));

#define K1_WRITE(SET, BUF) { \
  f16x8 h1, h2; \
  h1[0]=(_Float16)SET##a1a.x; h1[1]=(_Float16)SET##a1a.y; h1[2]=(_Float16)SET##a1a.z; h1[3]=(_Float16)SET##a1a.w; \
  h1[4]=(_Float16)SET##a1b.x; h1[5]=(_Float16)SET##a1b.y; h1[6]=(_Float16)SET##a1b.z; h1[7]=(_Float16)SET##a1b.w; \
  h2[0]=(_Float16)SET##a2a.x; h2[1]=(_Float16)SET##a2a.y; h2[2]=(_Float16)SET##a2a.z; h2[3]=(_Float16)SET##a2a.w; \
  h2[4]=(_Float16)SET##a2b.x; h2[5]=(_Float16)SET##a2b.y; h2[6]=(_Float16)SET##a2b.z; h2[7]=(_Float16)SET##a2b.w; \
  *(f16x8*)&Al[(BUF)][wA1] = h1; \
  *(f16x8*)&Al[(BUF)][wA2] = h2; \
  *(f16x8*)&Bh[(BUF)][wA1] = SET##vh1; \
  *(f16x8*)&Bh[(BUF)][wA2] = SET##vh2; }

#define K1_COMPUTE(BUF) { \
  const _Float16* Ab = &Al[(BUF)][0]; \
  const _Float16* Bhb = &Bh[(BUF)][0]; \
  f16x8 af[4], bhf[4]; \
  _Pragma("unroll") \
  for (int fm = 0; fm < 4; ++fm) af[fm] = *(const f16x8*)&Ab[aoff[fm]]; \
  _Pragma("unroll") \
  for (int fn = 0; fn < 4; ++fn) bhf[fn] = *(const f16x8*)&Bhb[boff[fn]]; \
  _Pragma("unroll") \
  for (int fm = 0; fm < 4; ++fm) \
    _Pragma("unroll") \
    for (int fn = 0; fn < 4; ++fn) \
      acc[fm][fn] = __builtin_amdgcn_mfma_f32_16x16x32_f16(af[fm], bhf[fn], acc[fm][fn], 0, 0, 0); }

  // prologue: step0 -> buf0 (via set A), step1 loads -> set B
  K1_LOAD(A, 0)
  K1_WRITE(A, 0)
  K1_LOAD(B, 32)
  __syncthreads();

  int cur = 0;
#pragma unroll 1
  for (int ks = 0; ks < 24; ks += 2) {
    // even iteration (step ks): compute buf[cur]; write setB (step ks+1)
    if (ks + 2 < 24) { K1_LOAD(A, (ks + 2) * 32) }
    K1_COMPUTE(cur)
    K1_WRITE(B, cur ^ 1)
    barrier_lds_only();
    cur ^= 1;
    // odd iteration (step ks+1): compute buf[cur]; write setA (step ks+2)
    if (ks + 3 < 24) { K1_LOAD(B, (ks + 3) * 32) }
    K1_COMPUTE(cur)
    if (ks + 2 < 24) { K1_WRITE(A, cur ^ 1) }
    barrier_lds_only();
    cur ^= 1;
  }
#undef K1_LOAD
#undef K1_WRITE
#undef K1_COMPUTE

  const int lq = lane >> 4;
  const int colbase = nt * 128 + wn * 64;
  const int ibase = mt * 128 + wm * 64;
  float* XUs = XU + (size_t)s * 4800 * 512;
  int rowm[4][4];
#pragma unroll
  for (int fm = 0; fm < 4; ++fm)
#pragma unroll
    for (int r = 0; r < 4; ++r) {
      const int i = ibase + fm * 16 + lq * 4 + r;
      rowm[fm][r] = (i < M) ? rms[i] : -1;
    }
#pragma unroll
  for (int fn = 0; fn < 4; ++fn) {
    const int col = colbase + fn * 16 + l15;
    const float bias = bU[s * 512 + col];
#pragma unroll
    for (int fm = 0; fm < 4; ++fm)
#pragma unroll
      for (int r = 0; r < 4; ++r) {
        const int row = rowm[fm][r];
        if (row >= 0) XUs[(size_t)row * 512 + col] = acc[fm][fn][r] + bias;
      }
  }
}

// ---------------------------------------------------------------------------
// K2 v9: MFMA time-LSTM (unchanged).
// ---------------------------------------------------------------------------
__global__ __launch_bounds__(512, 2) void k2_tlstm(const _Float16* __restrict__ Wfh,
                                                   const _Float16* __restrict__ Dfh,
                                                   const float* __restrict__ ball,
                                                   const float* __restrict__ bd,
                                                   const float* __restrict__ XU,
                                                   const float* __restrict__ times,
                                                   const int* __restrict__ lens,
                                                   float* __restrict__ outs,
                                                   float* __restrict__ hn) {
  const int s = blockIdx.x;
  const int mg = blockIdx.y;
  const int tid = threadIdx.x;
  const int w = tid >> 6, l = tid & 63;

  __shared__ _Float16 hhb[2][2048];
  __shared__ _Float16 chb[2][2048];
  __shared__ float xut[2][16 * 516];
  __shared__ float tsh[16 * 32];
  __shared__ int lensh[16];

  if (tid < 16) {
    const int n = mg * 16 + tid;
    lensh[tid] = lens[((n / 5) * 8 + s) * 5 + (n % 5)];
  }
  if (tid < 480) {
    const int r = tid / 30, c = tid % 30;
    const int n = mg * 16 + r;
    tsh[r * 32 + c] = times[(((n / 5) * 8 + s) * 5 + (n % 5)) * 30 + c];
  }

  f16x8 Bh[16], Dh[4];
  {
    const _Float16* wb = Wfh + (size_t)(s * 8 + w) * 8192 + l * 8;
    const _Float16* db = Dfh + (size_t)(s * 8 + w) * 2048 + l * 8;
#pragma unroll
    for (int c = 0; c < 16; ++c) Bh[c] = *(const f16x8*)&wb[c * 512];
#pragma unroll
    for (int c = 0; c < 4; ++c) Dh[c] = *(const f16x8*)&db[c * 512];
  }

  const int hd = w * 16 + (l & 15);
  const int rq0 = (l >> 4) * 4;
  const int lp0 = rq0 | (((hd >> 3) & 3) << 4);
  const int eoff0 = ((hd >> 5) * 64 + lp0) * 8 + (hd & 7);

#pragma unroll
  for (int q = 0; q < 4; ++q) {
    hhb[0][eoff0 + q * 8] = (_Float16)0.f;
    chb[0][eoff0 + q * 8] = (_Float16)0.f;
  }

  int n_q[4];
#pragma unroll
  for (int q = 0; q < 4; ++q) n_q[q] = mg * 16 + rq0 + q;
  float blr[4];
#pragma unroll
  for (int g = 0; g < 4; ++g) blr[g] = ball[s * 512 + g * 128 + hd];
  const float bdj = bd[s * 128 + hd];

  const int sr = tid >> 5;
  const int sc = tid & 31;
  const float* xsrc = XU + (size_t)(s * 160 + mg * 16 + sr) * 30 * 512 + sc * 4;
  const int xdst = sr * 516 + sc * 4;

  __syncthreads();

  int len_q[4];
  int maxlen = 0;
#pragma unroll
  for (int i = 0; i < 16; ++i) maxlen = max(maxlen, lensh[i]);
#pragma unroll
  for (int q = 0; q < 4; ++q) len_q[q] = lensh[rq0 + q];

  float creg[4] = {0.f, 0.f, 0.f, 0.f};
  float hreg[4] = {0.f, 0.f, 0.f, 0.f};
  float oprev[4] = {0.f, 0.f, 0.f, 0.f};

  {
    float4 v0 = *(const float4*)(xsrc);
    float4 v1 = *(const float4*)(xsrc + 128);
    float4 v2 = *(const float4*)(xsrc + 256);
    float4 v3 = *(const float4*)(xsrc + 384);
    *(float4*)&xut[0][xdst]       = v0;
    *(float4*)&xut[0][xdst + 128] = v1;
    *(float4*)&xut[0][xdst + 256] = v2;
    *(float4*)&xut[0][xdst + 384] = v3;
  }
  __syncthreads();

  for (int t = 0; t < maxlen; ++t) {
    const int p = t & 1;

    if (t > 0) {
      const int tp = t - 1;
#pragma unroll
      for (int q = 0; q < 4; ++q) {
        if (tp < len_q[q]) {
          outs[((size_t)(s * 160 + n_q[q]) * 30 + tp) * 128 + hd] = oprev[q];
          if (tp == len_q[q] - 1) hn[(size_t)(s * 160 + n_q[q]) * 128 + hd] = oprev[q];
        }
      }
    }

    float4 pv0, pv1, pv2, pv3;
    const bool more = (t + 1 < maxlen);
    if (more) {
      const float* xp = xsrc + (size_t)(t + 1) * 512;
      pv0 = *(const float4*)(xp);
      pv1 = *(const float4*)(xp + 128);
      pv2 = *(const float4*)(xp + 256);
      pv3 = *(const float4*)(xp + 384);
    }

    f32x4 amA[4], amB[4], dm;
#pragma unroll
    for (int g = 0; g < 4; ++g) {
      amA[g] = (f32x4){0.f, 0.f, 0.f, 0.f};
      amB[g] = (f32x4){0.f, 0.f, 0.f, 0.f};
    }
    dm = (f32x4){0.f, 0.f, 0.f, 0.f};
#pragma unroll
    for (int kt = 0; kt < 2; ++kt) {
      const f16x8 ah0 = *(const f16x8*)&hhb[p][(kt * 64 + l) * 8];
      const f16x8 ah1 = *(const f16x8*)&hhb[p][((kt + 2) * 64 + l) * 8];
      const f16x8 cf0 = *(const f16x8*)&chb[p][(kt * 64 + l) * 8];
      const f16x8 cf1 = *(const f16x8*)&chb[p][((kt + 2) * 64 + l) * 8];
#pragma unroll
      for (int g = 0; g < 4; ++g) {
        amA[g] = __builtin_amdgcn_mfma_f32_16x16x32_f16(ah0, Bh[kt * 4 + g], amA[g], 0, 0, 0);
        amB[g] = __builtin_amdgcn_mfma_f32_16x16x32_f16(ah1, Bh[(kt + 2) * 4 + g], amB[g], 0, 0, 0);
      }
      dm = __builtin_amdgcn_mfma_f32_16x16x32_f16(cf0, Dh[kt], dm, 0, 0, 0);
      dm = __builtin_amdgcn_mfma_f32_16x16x32_f16(cf1, Dh[kt + 2], dm, 0, 0, 0);
    }

#pragma unroll
    for (int q = 0; q < 4; ++q) {
      if (t < len_q[q]) {
        const float* xr = &xut[p][(rq0 + q) * 516 + hd];
        const float tt = tsh[(rq0 + q) * 32 + t];
        const float cs1 = tanhf_(dm[q] + bdj);
        const float f  = sigf(amA[0][q] + amB[0][q] + xr[0]   + blr[0]);
        const float ii = sigf(amA[1][q] + amB[1][q] + xr[128] + blr[1]);
        const float o  = sigf(amA[2][q] + amB[2][q] + xr[256] + blr[2]);
        const float ct = sigf(amA[3][q] + amB[3][q] + xr[384] + blr[3]);
        const float c2 = f * (creg[q] + cs1 * (tt - 1.f)) + ii * ct;
        creg[q] = c2;
        hreg[q] = o * tanhf_(c2);
        oprev[q] = o;
      }
      hhb[p ^ 1][eoff0 + q * 8] = (_Float16)hreg[q];
      chb[p ^ 1][eoff0 + q * 8] = (_Float16)creg[q];
    }

    if (more) {
      *(float4*)&xut[p ^ 1][xdst]       = pv0;
      *(float4*)&xut[p ^ 1][xdst + 128] = pv1;
      *(float4*)&xut[p ^ 1][xdst + 256] = pv2;
      *(float4*)&xut[p ^ 1][xdst + 384] = pv3;
    }
    barrier_lds_only();
  }

  {
    const int tp = maxlen - 1;
#pragma unroll
    for (int q = 0; q < 4; ++q) {
      if (tp >= 0 && tp < len_q[q]) {
        outs[((size_t)(s * 160 + n_q[q]) * 30 + tp) * 128 + hd] = oprev[q];
        if (tp == len_q[q] - 1) hn[(size_t)(s * 160 + n_q[q]) * 128 + hd] = oprev[q];
      }
    }
  }
}

// ---------------------------------------------------------------------------
// K3 v7: MFMA attention-1 with LDS-staged o-tile (unchanged).
// ---------------------------------------------------------------------------
__global__ __launch_bounds__(512, 2) void k3_attn1(const _Float16* __restrict__ W1f,
                                                   const _Float16* __restrict__ W2f,
                                                   const float* __restrict__ b1,
                                                   const float* __restrict__ b2,
                                                   const float* __restrict__ V,
                                                   const float* __restrict__ outs,
                                                   const float* __restrict__ hn,
                                                   const int* __restrict__ lens,
                                                   float* __restrict__ ctx) {
  const int s = blockIdx.x;
  const int sg = blockIdx.y;
  const int tid = threadIdx.x;
  const int w = tid >> 6, l = tid & 63;
  const int nbase = s * 160 + sg * 8;

  __shared__ _Float16 osh[32768];
  __shared__ float u[16][132];
  __shared__ float red[8][8][32];
  __shared__ float score[8][32];
  __shared__ int lensh[8];

  if (tid < 8) {
    const int n = sg * 8 + tid;
    lensh[tid] = lens[((n / 5) * 8 + s) * 5 + (n % 5)];
  }

#pragma unroll
  for (int i = 0; i < 8; ++i) {
    const int c = tid + i * 512;
    const int nl = c >> 9;
    const int th = (c >> 8) & 1;
    const int kt = (c >> 6) & 3;
    const int lp = c & 63;
    const int t15 = lp & 15;
    const int kb = kt * 32 + (lp >> 4) * 8;
    const int t = th * 16 + t15;
    f16x8 v;
    if (t < 30) {
      const float* src = outs + ((size_t)(nbase + nl) * 30 + t) * 128 + kb;
      const float4 a = *(const float4*)(src);
      const float4 b = *(const float4*)(src + 4);
      v[0]=(_Float16)a.x; v[1]=(_Float16)a.y; v[2]=(_Float16)a.z; v[3]=(_Float16)a.w;
      v[4]=(_Float16)b.x; v[5]=(_Float16)b.y; v[6]=(_Float16)b.z; v[7]=(_Float16)b.w;
    } else {
      v = (f16x8){(_Float16)0.f,(_Float16)0.f,(_Float16)0.f,(_Float16)0.f,
                  (_Float16)0.f,(_Float16)0.f,(_Float16)0.f,(_Float16)0.f};
    }
    *(f16x8*)&osh[c * 8] = v;
  }

  f16x8 W1r[4], W2r[4];
  {
    const _Float16* w1b = W1f + (size_t)(s * 8 + w) * 2048 + l * 8;
    const _Float16* w2b = W2f + (size_t)(s * 8 + w) * 2048 + l * 8;
#pragma unroll
    for (int kt = 0; kt < 4; ++kt) {
      W1r[kt] = *(const f16x8*)&w1b[kt * 512];
      W2r[kt] = *(const f16x8*)&w2b[kt * 512];
    }
  }

  const int hd = w * 16 + (l & 15);
  const float Vhd = V[s * 128 + hd];
  const float b12 = b1[s * 128 + hd] + b2[s * 128 + hd];
  const int kc = (l >> 4) << 3;

  {
    const int rsrc = min(l & 15, 7);
    f32x4 dm = (f32x4){0.f, 0.f, 0.f, 0.f};
#pragma unroll
    for (int kt = 0; kt < 4; ++kt) {
      const float* hp = hn + (size_t)(nbase + rsrc) * 128 + kt * 32 + kc;
      const float4 a = *(const float4*)(hp);
      const float4 b = *(const float4*)(hp + 4);
      f16x8 ah;
      ah[0]=(_Float16)a.x; ah[1]=(_Float16)a.y; ah[2]=(_Float16)a.z; ah[3]=(_Float16)a.w;
      ah[4]=(_Float16)b.x; ah[5]=(_Float16)b.y; ah[6]=(_Float16)b.z; ah[7]=(_Float16)b.w;
      dm = __builtin_amdgcn_mfma_f32_16x16x32_f16(ah, W1r[kt], dm, 0, 0, 0);
    }
#pragma unroll
    for (int q = 0; q < 4; ++q) u[(l >> 4) * 4 + q][hd] = dm[q] + b12;
  }
  __syncthreads();

#pragma unroll
  for (int m = 0; m < 16; ++m) {
    const int nl = m >> 1, th = m & 1;
    const int cbase = ((nl * 2 + th) * 4) * 64;
    f32x4 acc = (f32x4){0.f, 0.f, 0.f, 0.f};
#pragma unroll
    for (int kt = 0; kt < 4; ++kt) {
      const f16x8 ah = *(const f16x8*)&osh[(cbase + kt * 64 + l) * 8];
      acc = __builtin_amdgcn_mfma_f32_16x16x32_f16(ah, W2r[kt], acc, 0, 0, 0);
    }
    const float uv = u[nl][hd];
#pragma unroll
    for (int q = 0; q < 4; ++q) {
      float p = tanhf_(acc[q] + uv) * Vhd;
      p += __shfl_xor(p, 1);
      p += __shfl_xor(p, 2);
      p += __shfl_xor(p, 4);
      p += __shfl_xor(p, 8);
      const int t = th * 16 + (l >> 4) * 4 + q;
      if ((l & 15) == 0 && t < 30) red[w][nl][t] = p;
    }
  }
  __syncthreads();

  if (tid < 256) {
    const int nl = tid >> 5, t = tid & 31;
    if (t < 30) {
      float sc = 0.f;
#pragma unroll
      for (int ww = 0; ww < 8; ++ww) sc += red[ww][nl][t];
      score[nl][t] = sc;
    }
  }
  __syncthreads();

  {
    const int nl = tid >> 6, jg = tid & 63;
    const int len = lensh[nl];
    float mx = -1e30f;
    for (int t = 0; t < len; ++t) mx = fmaxf(mx, score[nl][t]);
    const float* ob = outs + (size_t)(nbase + nl) * 30 * 128 + jg * 2;
    float sum = 0.f;
    float cx0 = 0.f, cx1 = 0.f;
    for (int t = 0; t < len; ++t) {
      const float e = __expf(score[nl][t] - mx);
      sum += e;
      const float2 o2 = *(const float2*)(ob + (size_t)t * 128);
      cx0 += e * o2.x; cx1 += e * o2.y;
    }
    const float r = rcp_(sum);
    float2 res = {cx0 * r, cx1 * r};
    *(float2*)&ctx[(size_t)(nbase + nl) * 128 + jg * 2] = res;
  }
}

// ---------------------------------------------------------------------------
// K45: FUSED lstm2 + attention2 + output MLP (unchanged from round 17).
// ---------------------------------------------------------------------------
__global__ __launch_bounds__(512, 2) void k45_fused(const float* __restrict__ Wih,
                                                    const float* __restrict__ bih,
                                                    const float* __restrict__ Whh,
                                                    const float* __restrict__ bhh,
                                                    const float* __restrict__ aW1,
                                                    const float* __restrict__ ab1,
                                                    const float* __restrict__ aW2,
                                                    const float* __restrict__ ab2,
                                                    const float* __restrict__ aV,
                                                    const float* __restrict__ x1W,
                                                    const float* __restrict__ x1b,
                                                    const float* __restrict__ x2W,
                                                    const float* __restrict__ x2b,
                                                    const float* __restrict__ ctx,
                                                    float* __restrict__ y) {
  const int s = blockIdx.y, b = blockIdx.x;
  const int tid = threadIdx.x;
  __shared__ float xs[5][128];
  __shared__ float hsm[5][128];
  __shared__ float hcur[128];
  __shared__ float gsh[512];
  __shared__ float red[4][128];
  __shared__ float wred[2];
  __shared__ float sc[5];
  __shared__ float u_sh[128];
  __shared__ float cs2[128];
  __shared__ float t1[128];
  __shared__ float red2[8][64];

  for (int idx = tid; idx < 640; idx += 512)
    (&xs[0][0])[idx] = ctx[(size_t)(s * 160 + b * 5) * 128 + idx];
  if (tid < 128) hcur[tid] = 0.f;
  __syncthreads();

  const float* Wis = Wih + (size_t)s * 65536;
  const float* Whs = Whh + (size_t)s * 65536;
  const float bias = bih[s * 512 + tid] + bhh[s * 512 + tid];
  float xw[5] = {bias, bias, bias, bias, bias};
  float whh[128];
#pragma unroll
  for (int k = 0; k < 128; ++k) {
    const float wi = Wis[k * 512 + tid];
    whh[k] = Whs[k * 512 + tid];
#pragma unroll
    for (int dd = 0; dd < 5; ++dd) xw[dd] += xs[dd][k] * wi;
  }

  float c = 0.f;
  for (int dd = 0; dd < 5; ++dd) {
    float g = xw[dd];
#pragma unroll
    for (int k = 0; k < 128; ++k) g += hcur[k] * whh[k];
    gsh[tid] = g;
    __syncthreads();
    if (tid < 128) {
      const int j = tid;
      const float c2 = sigf(gsh[128 + j]) * c + sigf(gsh[j]) * tanhf_(gsh[256 + j]);
      const float h2 = sigf(gsh[384 + j]) * tanhf_(c2);
      c = c2;
      hcur[j] = h2;
      hsm[dd][j] = h2;
    }
    __syncthreads();
  }

  const int q = tid >> 7, j = tid & 127;
  const float* W1s = aW1 + (size_t)s * 16384;
  const float* W2s = aW2 + (size_t)s * 16384;

  {
    float part = 0.f;
#pragma unroll
    for (int k = 0; k < 32; ++k) part += hsm[4][q * 32 + k] * W1s[(q * 32 + k) * 128 + j];
    red[q][j] = part;
  }
  __syncthreads();
  if (tid < 128)
    u_sh[j] = red[0][j] + red[1][j] + red[2][j] + red[3][j] +
              ab1[s * 128 + j] + ab2[s * 128 + j];
  __syncthreads();

  for (int d = 0; d < 5; ++d) {
    float part = 0.f;
#pragma unroll
    for (int k = 0; k < 32; ++k) part += hsm[d][q * 32 + k] * W2s[(q * 32 + k) * 128 + j];
    red[q][j] = part;
    __syncthreads();
    if (tid < 128) {
      float a = u_sh[j] + red[0][j] + red[1][j] + red[2][j] + red[3][j];
      float pv = tanhf_(a) * aV[s * 128 + j];
#pragma unroll
      for (int off = 32; off; off >>= 1) pv += __shfl_down(pv, off);
      if ((tid & 63) == 0) wred[tid >> 6] = pv;
    }
    __syncthreads();
    if (tid == 0) sc[d] = wred[0] + wred[1];
    __syncthreads();
  }

  if (tid < 128) {
    float m = sc[0];
#pragma unroll
    for (int d = 1; d < 5; ++d) m = fmaxf(m, sc[d]);
    float e[5], sum = 0.f;
#pragma unroll
    for (int d = 0; d < 5; ++d) { e[d] = __expf(sc[d] - m); sum += e[d]; }
    float cx = 0.f;
#pragma unroll
    for (int d = 0; d < 5; ++d) cx += e[d] * hsm[d][j];
    cs2[j] = cx * rcp_(sum);
  }
  __syncthreads();

  {
    float part = 0.f;
#pragma unroll
    for (int k = 0; k < 32; ++k) part += cs2[q * 32 + k] * x1W[(size_t)s * 16384 + (q * 32 + k) * 128 + j];
    red[q][j] = part;
  }
  __syncthreads();
  if (tid < 128)
    t1[j] = fmaxf(red[0][j] + red[1][j] + red[2][j] + red[3][j] + x1b[s * 128 + j], 0.f);
  __syncthreads();

  {
    const int q2 = tid >> 6, j2 = tid & 63;
    float part = 0.f;
#pragma unroll
    for (int k = 0; k < 16; ++k) part += t1[q2 * 16 + k] * x2W[(size_t)s * 8192 + (q2 * 16 + k) * 64 + j2];
    red2[q2][j2] = part;
  }
  __syncthreads();
  if (tid < 64) {
    float yy = x2b[s * 64 + tid];
#pragma unroll
    for (int g = 0; g < 8; ++g) yy += red2[g][tid];
    y[(size_t)(s * 32 + b) * 64 + tid] = yy;
  }
}

// ---------------------------------------------------------------------------
// K6: final combine (unchanged).
// ---------------------------------------------------------------------------
__global__ __launch_bounds__(256) void k6_final(const float* __restrict__ stock,
                                                const float* __restrict__ h1W,
                                                const float* __restrict__ h1b,
                                                const float* __restrict__ h2W,
                                                const float* __restrict__ h2b,
                                                const float* __restrict__ hcW,
                                                const float* __restrict__ hcb,
                                                const float* __restrict__ yws,
                                                float* __restrict__ out) {
  const int tid = threadIdx.x;
  __shared__ float sf[32 * 17];
  __shared__ float hid[32 * 64];
  __shared__ float xs[32 * 32];
  for (int idx = tid; idx < 544; idx += 256) sf[idx] = stock[idx];
  __syncthreads();
  for (int idx = tid; idx < 2048; idx += 256) {
    const int b = idx >> 6, k = idx & 63;
    float a = h1b[k];
    for (int q = 0; q < 17; ++q) a += sf[b * 17 + q] * h1W[q * 64 + k];
    hid[idx] = fmaxf(a, 0.f);
  }
  __syncthreads();
  for (int idx = tid; idx < 1024; idx += 256) {
    const int b = idx >> 5, mm = idx & 31;
    float a = h2b[mm];
    for (int k = 0; k < 64; ++k) a += hid[b * 64 + k] * h2W[k * 32 + mm];
    xs[idx] = a;
  }
  __syncthreads();
  {
    const int b = tid >> 3, o = tid & 7;
    float a = hcb[o];
    for (int c = 0; c < 32; ++c) a += xs[b * 32 + c] * hcW[c * 8 + o];
    for (int c = 32; c < 544; ++c) {
      const int ss = (c - 32) >> 6, k = (c - 32) & 63;
      a += yws[((size_t)ss * 32 + b) * 64 + k] * hcW[c * 8 + o];
    }
    out[tid] = tanhf_(a);
  }
}

// ---------------------------------------------------------------------------
extern "C" void kernel_launch(void* const* d_in, const int* in_sizes, int n_in,
                              void* d_out, int out_size, void* d_ws, size_t ws_size,
                              hipStream_t stream) {
  (void)in_sizes; (void)n_in; (void)out_size; (void)ws_size;
  const float* stock = (const float*)d_in[0];
  const float* sent  = (const float*)d_in[1];
  const float* times = (const float*)d_in[2];
  const int*   lens  = (const int*)d_in[3];
  const float* tlWall = (const float*)d_in[4];
  const float* tlball = (const float*)d_in[5];
  const float* tlUall = (const float*)d_in[6];
  const float* tlbU   = (const float*)d_in[7];
  const float* tlWd   = (const float*)d_in[8];
  const float* tlbd   = (const float*)d_in[9];
  const float* a1W1 = (const float*)d_in[10];
  const float* a1b1 = (const float*)d_in[11];
  const float* a1W2 = (const float*)d_in[12];
  const float* a1b2 = (const float*)d_in[13];
  const float* a1V  = (const float*)d_in[14];
  const float* a1bV = (const float*)d_in[15];
  const float* l2Wih = (const float*)d_in[16];
  const float* l2bih = (const float*)d_in[17];
  const float* l2Whh = (const float*)d_in[18];
  const float* l2bhh = (const float*)d_in[19];
  const float* a2W1 = (const float*)d_in[20];
  const float* a2b1 = (const float*)d_in[21];
  const float* a2W2 = (const float*)d_in[22];
  const float* a2b2 = (const float*)d_in[23];
  const float* a2V  = (const float*)d_in[24];
  const float* a2bV = (const float*)d_in[25];
  const float* x1W  = (const float*)d_in[26];
  const float* x1b  = (const float*)d_in[27];
  const float* x2W  = (const float*)d_in[28];
  const float* x2b  = (const float*)d_in[29];
  const float* h1W  = (const float*)d_in[30];
  const float* h1b  = (const float*)d_in[31];
  const float* h2W  = (const float*)d_in[32];
  const float* h2b  = (const float*)d_in[33];
  const float* hcW  = (const float*)d_in[34];
  const float* hcb  = (const float*)d_in[35];
  (void)a1bV; (void)a2bV;

  float* ws = (float*)d_ws;
  float* XU    = ws;               // 8*160*30*512   = 19,660,800
  float* outs  = XU + 19660800;    // 8*160*30*128   =  4,915,200
  float* hnb   = outs + 4915200;   // 8*160*128      =    163,840
  float* ctx   = hnb + 163840;     // 8*160*128      =    163,840
  float* yb    = ctx + 163840;     // 8*32*64        =     16,384
  _Float16* Uhw = (_Float16*)(yb + 16384);    // 8*512*768 halfs
  _Float16* Wfh = Uhw + 8 * 512 * 768;        // 8*8*8192 halfs
  _Float16* Dfh = Wfh + 8 * 8 * 8192;         // 8*8*2048 halfs
  _Float16* W1f = Dfh + 8 * 8 * 2048;         // 8*8*2048 halfs
  _Float16* W2f = W1f + 8 * 8 * 2048;         // 8*8*2048 halfs
  int* rowmap = (int*)(W2f + 8 * 8 * 2048);   // 8*4800 ints
  int* Msd    = rowmap + 8 * 4800;            // 8 ints

  k0_rowmap<<<8, 256, 0, stream>>>(lens, rowmap, Msd);
  k0_usplit<<<dim3(12, 8, 8), 256, 0, stream>>>(tlUall, Uhw);
  k0_wprep<<<dim3(8, 8), 256, 0, stream>>>(tlWall, tlWd, Wfh, Dfh);
  k0_aprep<<<dim3(8, 8), 256, 0, stream>>>(a1W1, a1W2, W1f, W2f);
  k1_xu<<<dim3(8, 152), 256, 0, stream>>>(sent, Uhw, tlbU, rowmap, Msd, XU);
  k2_tlstm<<<dim3(8, 10), 512, 0, stream>>>(Wfh, Dfh, tlball, tlbd, XU, times, lens, outs, hnb);
  k3_attn1<<<dim3(8, 20), 512, 0, stream>>>(W1f, W2f, a1b1, a1b2, a1V, outs, hnb, lens, ctx);
  k45_fused<<<dim3(32, 8), 512, 0, stream>>>(l2Wih, l2bih, l2Whh, l2bhh,
                                             a2W1, a2b1, a2W2, a2b2, a2V,
                                             x1W, x1b, x2W, x2b, ctx, yb);
  k6_final<<<1, 256, 0, stream>>>(stock, h1W, h1b, h2W, h2b, hcW, hcb, yb, (float*)d_out);
}

// Round 19
// 204.439 us; speedup vs baseline: 1.3768x; 1.3768x over previous
//
#include <hip/hip_runtime.h>
#include <cstddef>

// Problem constants: S=8, B=32, D=5, T=30, E=768, H=128, 4H=512.

typedef __attribute__((ext_vector_type(8))) _Float16 f16x8;
typedef __attribute__((ext_vector_type(4))) _Float16 f16x4;
typedef __attribute__((ext_vector_type(2))) _Float16 f16x2;
typedef __attribute__((ext_vector_type(4))) float f32x4;

__device__ __forceinline__ float rcp_(float x) { return __builtin_amdgcn_rcpf(x); }
__device__ __forceinline__ float sigf(float x) { return rcp_(1.0f + __expf(-x)); }
__device__ __forceinline__ float tanhf_(float x) { return 1.0f - 2.0f * rcp_(__expf(2.0f * x) + 1.0f); }

// LDS-only barrier: drains lgkmcnt but NOT vmcnt (global ops stay in flight).
__device__ __forceinline__ void barrier_lds_only() {
  asm volatile("s_waitcnt lgkmcnt(0)" ::: "memory");
  __builtin_amdgcn_s_barrier();
  __builtin_amdgcn_sched_barrier(0);
}

// ---------------------------------------------------------------------------
// K0r: per-stock compacted row map: rows (n,t) with t < len[s,n].
// ---------------------------------------------------------------------------
__global__ __launch_bounds__(256) void k0_rowmap(const int* __restrict__ lens,
                                                 int* __restrict__ rowmap,
                                                 int* __restrict__ Ms) {
  const int s = blockIdx.x;
  const int tid = threadIdx.x;
  __shared__ int st[160];
  __shared__ int ln[160];
  if (tid < 160) {
    const int b = tid / 5, d = tid % 5;
    ln[tid] = lens[(b * 8 + s) * 5 + d];
  }
  __syncthreads();
  if (tid == 0) {
    int run = 0;
    for (int n = 0; n < 160; ++n) { st[n] = run; run += ln[n]; }
    Ms[s] = run;
  }
  __syncthreads();
  if (tid < 160) {
    const int base = st[tid], l = ln[tid];
    for (int t = 0; t < l; ++t) rowmap[s * 4800 + base + t] = tid * 30 + t;
  }
}

// ---------------------------------------------------------------------------
// K0: transpose U to fp16 (hi only) via LDS tiles (for k1).
// ---------------------------------------------------------------------------
__global__ __launch_bounds__(256) void k0_usplit(const float* __restrict__ U,
                                                 _Float16* __restrict__ Uh) {
  const int s = blockIdx.z;
  const int k0 = blockIdx.x * 64;
  const int n0 = blockIdx.y * 64;
  const int tid = threadIdx.x;
  __shared__ _Float16 Th[64 * 66];
  const float* Us = U + (size_t)s * 768 * 512;
#pragma unroll
  for (int rep = 0; rep < 16; ++rep) {
    const int idx = rep * 256 + tid;
    const int r = idx >> 6, c = idx & 63;
    Th[r * 66 + c] = (_Float16)Us[(size_t)(k0 + r) * 512 + n0 + c];
  }
  __syncthreads();
  _Float16* uhs = Uh + (size_t)s * 512 * 768;
#pragma unroll
  for (int rep = 0; rep < 8; ++rep) {
    const int idx = rep * 256 + tid;
    const int nn = idx >> 5;
    const int kp = (idx & 31) * 2;
    const f16x2 h2 = {Th[kp * 66 + nn], Th[(kp + 1) * 66 + nn]};
    *(f16x2*)&uhs[(size_t)(n0 + nn) * 768 + k0 + kp] = h2;
  }
}

// ---------------------------------------------------------------------------
// K0w: pack Wall (hi only) and Wd (hi) into MFMA B-fragment-linear layout.
// ---------------------------------------------------------------------------
__global__ __launch_bounds__(256) void k0_wprep(const float* __restrict__ Wall,
                                                const float* __restrict__ Wd,
                                                _Float16* __restrict__ Wfh,
                                                _Float16* __restrict__ Dfh) {
  const int w = blockIdx.x, s = blockIdx.y;
  const int tid = threadIdx.x;
  const float* Ws = Wall + (size_t)s * 65536;
  _Float16* oh = Wfh + (size_t)(s * 8 + w) * 8192;
  for (int c = tid; c < 1024; c += 256) {
    const int kt = c >> 8, nt = (c >> 6) & 3, l = c & 63;
    const int n = nt * 128 + w * 16 + (l & 15);   // gate-major per wave
    const int kb = kt * 32 + ((l >> 4) << 3);
    f16x8 hv;
#pragma unroll
    for (int e = 0; e < 8; ++e) hv[e] = (_Float16)Ws[(size_t)(kb + e) * 512 + n];
    *(f16x8*)&oh[c * 8] = hv;
  }
  {
    const float* Ds = Wd + (size_t)s * 16384;
    _Float16* od = Dfh + (size_t)(s * 8 + w) * 2048;
    const int c = tid;
    const int kt = c >> 6, l = c & 63;
    const int n = w * 16 + (l & 15);
    const int kb = kt * 32 + ((l >> 4) << 3);
    f16x8 hv;
#pragma unroll
    for (int e = 0; e < 8; ++e) hv[e] = (_Float16)Ds[(size_t)(kb + e) * 128 + n];
    *(f16x8*)&od[c * 8] = hv;
  }
}

// ---------------------------------------------------------------------------
// K0a: pack a1_W1 and a1_W2 into per-wave 16-col B-frag layout.
// ---------------------------------------------------------------------------
__global__ __launch_bounds__(256) void k0_aprep(const float* __restrict__ W1,
                                                const float* __restrict__ W2,
                                                _Float16* __restrict__ W1f,
                                                _Float16* __restrict__ W2f) {
  const int w = blockIdx.x, s = blockIdx.y;
  const int c = threadIdx.x;          // 0..255 = kt*64 + l
  const int kt = c >> 6, l = c & 63;
  const int n = w * 16 + (l & 15);
  const int kb = kt * 32 + ((l >> 4) << 3);
  const float* W1s = W1 + (size_t)s * 16384;
  const float* W2s = W2 + (size_t)s * 16384;
  f16x8 v1, v2;
#pragma unroll
  for (int e = 0; e < 8; ++e) {
    v1[e] = (_Float16)W1s[(size_t)(kb + e) * 128 + n];
    v2[e] = (_Float16)W2s[(size_t)(kb + e) * 128 + n];
  }
  *(f16x8*)&W1f[(size_t)(s * 8 + w) * 2048 + c * 8] = v1;
  *(f16x8*)&W2f[(size_t)(s * 8 + w) * 2048 + c * 8] = v2;
}

// ---------------------------------------------------------------------------
// K1 v5 (REVERT from v6: prefetch-2 spilled to scratch, WRITE_SIZE 48->225MB).
//   XU = x @ U + bU via MFMA, single fp16 product, XCD-pinned grid,
//   LDS-only K-loop barrier. Best measured: 73.5 us.
// ---------------------------------------------------------------------------
__global__ __launch_bounds__(256, 4) void k1_xu(const float* __restrict__ sent,
                                                const _Float16* __restrict__ Uh,
                                                const float* __restrict__ bU,
                                                const int* __restrict__ rowmap,
                                                const int* __restrict__ Ms,
                                                float* __restrict__ XU) {
  const int s = blockIdx.x;
  const int M = Ms[s];
  const int nt = blockIdx.y & 3;
  const int mt = blockIdx.y >> 2;
  if (mt * 128 >= M) return;
  const int tid = threadIdx.x;
  const int lane = tid & 63, wid = tid >> 6;
  const int wm = wid >> 1, wn = wid & 1;

  __shared__ _Float16 Al[2][128 * 32];
  __shared__ _Float16 Bh[2][128 * 32];

  const int ar1 = tid >> 2;
  const int chk = tid & 3;
  const int afk = chk * 8;
  const int fw = (ar1 ^ (ar1 >> 2)) & 3;
  const int wA1 = ar1 * 32 + ((chk ^ fw) * 8);
  const int wA2 = wA1 + 64 * 32;

  const int* rms = rowmap + s * 4800;
  const float* asrc1;
  const float* asrc2;
  {
    int i1 = mt * 128 + ar1; if (i1 > M - 1) i1 = M - 1;
    const int grow = rms[i1];
    const int nn = grow / 30, tt = grow % 30, ab = nn / 5, ad = nn % 5;
    asrc1 = sent + (size_t)((((ab * 8 + s) * 5 + ad) * 30) + tt) * 768 + afk;
  }
  {
    int i2 = mt * 128 + ar1 + 64; if (i2 > M - 1) i2 = M - 1;
    const int grow = rms[i2];
    const int nn = grow / 30, tt = grow % 30, ab = nn / 5, ad = nn % 5;
    asrc2 = sent + (size_t)((((ab * 8 + s) * 5 + ad) * 30) + tt) * 768 + afk;
  }
  const _Float16* UhS = Uh + (size_t)s * 512 * 768;
  const _Float16* bh1 = UhS + (size_t)(nt * 128 + ar1) * 768 + afk;
  const _Float16* bh2 = UhS + (size_t)(nt * 128 + ar1 + 64) * 768 + afk;

  const int q = lane >> 4;
  const int l15 = lane & 15;
  int aoff[4], boff[4];
#pragma unroll
  for (int f = 0; f < 4; ++f) {
    {
      const int row = wm * 64 + f * 16 + l15;
      const int fr = (row ^ (row >> 2)) & 3;
      aoff[f] = row * 32 + ((q ^ fr) * 8);
    }
    {
      const int row = wn * 64 + f * 16 + l15;
      const int fr = (row ^ (row >> 2)) & 3;
      boff[f] = row * 32 + ((q ^ fr) * 8);
    }
  }

  f32x4 acc[4][4];
#pragma unroll
  for (int i = 0; i < 4; ++i)
#pragma unroll
    for (int j = 0; j < 4; ++j) acc[i][j] = (f32x4){0.f, 0.f, 0.f, 0.f};

  {
    const float4 a1a = *(const float4*)(asrc1);
    const float4 a1b = *(const float4*)(asrc1 + 4);
    const float4 a2a = *(const float4*)(asrc2);
    const float4 a2b = *(const float4*)(asrc2 + 4);
    const f16x8 vh1 = *(const f16x8*)(bh1);
    const f16x8 vh2 = *(const f16x8*)(bh2);
    f16x8 h1, h2;
    h1[0]=(_Float16)a1a.x; h1[1]=(_Float16)a1a.y; h1[2]=(_Float16)a1a.z; h1[3]=(_Float16)a1a.w;
    h1[4]=(_Float16)a1b.x; h1[5]=(_Float16)a1b.y; h1[6]=(_Float16)a1b.z; h1[7]=(_Float16)a1b.w;
    h2[0]=(_Float16)a2a.x; h2[1]=(_Float16)a2a.y; h2[2]=(_Float16)a2a.z; h2[3]=(_Float16)a2a.w;
    h2[4]=(_Float16)a2b.x; h2[5]=(_Float16)a2b.y; h2[6]=(_Float16)a2b.z; h2[7]=(_Float16)a2b.w;
    *(f16x8*)&Al[0][wA1] = h1;
    *(f16x8*)&Al[0][wA2] = h2;
    *(f16x8*)&Bh[0][wA1] = vh1;
    *(f16x8*)&Bh[0][wA2] = vh2;
  }
  __syncthreads();

  int cur = 0;
  for (int ks = 0; ks < 24; ++ks) {
    const int nxt = cur ^ 1;
    const bool more = (ks < 23);
    float4 a1a, a1b, a2a, a2b;
    f16x8 vh1, vh2;
    if (more) {
      const int ko = (ks + 1) * 32;
      a1a = *(const float4*)(asrc1 + ko);
      a1b = *(const float4*)(asrc1 + ko + 4);
      a2a = *(const float4*)(asrc2 + ko);
      a2b = *(const float4*)(asrc2 + ko + 4);
      vh1 = *(const f16x8*)(bh1 + ko);
      vh2 = *(const f16x8*)(bh2 + ko);
    }
    {
      const _Float16* Ab = &Al[cur][0];
      const _Float16* Bhb = &Bh[cur][0];
      f16x8 af[4], bhf[4];
#pragma unroll
      for (int fm = 0; fm < 4; ++fm) af[fm] = *(const f16x8*)&Ab[aoff[fm]];
#pragma unroll
      for (int fn = 0; fn < 4; ++fn) bhf[fn] = *(const f16x8*)&Bhb[boff[fn]];
#pragma unroll
      for (int fm = 0; fm < 4; ++fm)
#pragma unroll
        for (int fn = 0; fn < 4; ++fn)
          acc[fm][fn] = __builtin_amdgcn_mfma_f32_16x16x32_f16(af[fm], bhf[fn], acc[fm][fn], 0, 0, 0);
    }
    if (more) {
      f16x8 h1, h2;
      h1[0]=(_Float16)a1a.x; h1[1]=(_Float16)a1a.y; h1[2]=(_Float16)a1a.z; h1[3]=(_Float16)a1a.w;
      h1[4]=(_Float16)a1b.x; h1[5]=(_Float16)a1b.y; h1[6]=(_Float16)a1b.z; h1[7]=(_Float16)a1b.w;
      h2[0]=(_Float16)a2a.x; h2[1]=(_Float16)a2a.y; h2[2]=(_Float16)a2a.z; h2[3]=(_Float16)a2a.w;
      h2[4]=(_Float16)a2b.x; h2[5]=(_Float16)a2b.y; h2[6]=(_Float16)a2b.z; h2[7]=(_Float16)a2b.w;
      *(f16x8*)&Al[nxt][wA1] = h1;
      *(f16x8*)&Al[nxt][wA2] = h2;
      *(f16x8*)&Bh[nxt][wA1] = vh1;
      *(f16x8*)&Bh[nxt][wA2] = vh2;
    }
    barrier_lds_only();
    cur = nxt;
  }

  const int lq = lane >> 4;
  const int colbase = nt * 128 + wn * 64;
  const int ibase = mt * 128 + wm * 64;
  float* XUs = XU + (size_t)s * 4800 * 512;
  int rowm[4][4];
#pragma unroll
  for (int fm = 0; fm < 4; ++fm)
#pragma unroll
    for (int r = 0; r < 4; ++r) {
      const int i = ibase + fm * 16 + lq * 4 + r;
      rowm[fm][r] = (i < M) ? rms[i] : -1;
    }
#pragma unroll
  for (int fn = 0; fn < 4; ++fn) {
    const int col = colbase + fn * 16 + l15;
    const float bias = bU[s * 512 + col];
#pragma unroll
    for (int fm = 0; fm < 4; ++fm)
#pragma unroll
      for (int r = 0; r < 4; ++r) {
        const int row = rowm[fm][r];
        if (row >= 0) XUs[(size_t)row * 512 + col] = acc[fm][fn][r] + bias;
      }
  }
}

// ---------------------------------------------------------------------------
// K2 v9: MFMA time-LSTM (unchanged).
// ---------------------------------------------------------------------------
__global__ __launch_bounds__(512, 2) void k2_tlstm(const _Float16* __restrict__ Wfh,
                                                   const _Float16* __restrict__ Dfh,
                                                   const float* __restrict__ ball,
                                                   const float* __restrict__ bd,
                                                   const float* __restrict__ XU,
                                                   const float* __restrict__ times,
                                                   const int* __restrict__ lens,
                                                   float* __restrict__ outs,
                                                   float* __restrict__ hn) {
  const int s = blockIdx.x;
  const int mg = blockIdx.y;
  const int tid = threadIdx.x;
  const int w = tid >> 6, l = tid & 63;

  __shared__ _Float16 hhb[2][2048];
  __shared__ _Float16 chb[2][2048];
  __shared__ float xut[2][16 * 516];
  __shared__ float tsh[16 * 32];
  __shared__ int lensh[16];

  if (tid < 16) {
    const int n = mg * 16 + tid;
    lensh[tid] = lens[((n / 5) * 8 + s) * 5 + (n % 5)];
  }
  if (tid < 480) {
    const int r = tid / 30, c = tid % 30;
    const int n = mg * 16 + r;
    tsh[r * 32 + c] = times[(((n / 5) * 8 + s) * 5 + (n % 5)) * 30 + c];
  }

  f16x8 Bh[16], Dh[4];
  {
    const _Float16* wb = Wfh + (size_t)(s * 8 + w) * 8192 + l * 8;
    const _Float16* db = Dfh + (size_t)(s * 8 + w) * 2048 + l * 8;
#pragma unroll
    for (int c = 0; c < 16; ++c) Bh[c] = *(const f16x8*)&wb[c * 512];
#pragma unroll
    for (int c = 0; c < 4; ++c) Dh[c] = *(const f16x8*)&db[c * 512];
  }

  const int hd = w * 16 + (l & 15);
  const int rq0 = (l >> 4) * 4;
  const int lp0 = rq0 | (((hd >> 3) & 3) << 4);
  const int eoff0 = ((hd >> 5) * 64 + lp0) * 8 + (hd & 7);

#pragma unroll
  for (int q = 0; q < 4; ++q) {
    hhb[0][eoff0 + q * 8] = (_Float16)0.f;
    chb[0][eoff0 + q * 8] = (_Float16)0.f;
  }

  int n_q[4];
#pragma unroll
  for (int q = 0; q < 4; ++q) n_q[q] = mg * 16 + rq0 + q;
  float blr[4];
#pragma unroll
  for (int g = 0; g < 4; ++g) blr[g] = ball[s * 512 + g * 128 + hd];
  const float bdj = bd[s * 128 + hd];

  const int sr = tid >> 5;
  const int sc = tid & 31;
  const float* xsrc = XU + (size_t)(s * 160 + mg * 16 + sr) * 30 * 512 + sc * 4;
  const int xdst = sr * 516 + sc * 4;

  __syncthreads();

  int len_q[4];
  int maxlen = 0;
#pragma unroll
  for (int i = 0; i < 16; ++i) maxlen = max(maxlen, lensh[i]);
#pragma unroll
  for (int q = 0; q < 4; ++q) len_q[q] = lensh[rq0 + q];

  float creg[4] = {0.f, 0.f, 0.f, 0.f};
  float hreg[4] = {0.f, 0.f, 0.f, 0.f};
  float oprev[4] = {0.f, 0.f, 0.f, 0.f};

  {
    float4 v0 = *(const float4*)(xsrc);
    float4 v1 = *(const float4*)(xsrc + 128);
    float4 v2 = *(const float4*)(xsrc + 256);
    float4 v3 = *(const float4*)(xsrc + 384);
    *(float4*)&xut[0][xdst]       = v0;
    *(float4*)&xut[0][xdst + 128] = v1;
    *(float4*)&xut[0][xdst + 256] = v2;
    *(float4*)&xut[0][xdst + 384] = v3;
  }
  __syncthreads();

  for (int t = 0; t < maxlen; ++t) {
    const int p = t & 1;

    if (t > 0) {
      const int tp = t - 1;
#pragma unroll
      for (int q = 0; q < 4; ++q) {
        if (tp < len_q[q]) {
          outs[((size_t)(s * 160 + n_q[q]) * 30 + tp) * 128 + hd] = oprev[q];
          if (tp == len_q[q] - 1) hn[(size_t)(s * 160 + n_q[q]) * 128 + hd] = oprev[q];
        }
      }
    }

    float4 pv0, pv1, pv2, pv3;
    const bool more = (t + 1 < maxlen);
    if (more) {
      const float* xp = xsrc + (size_t)(t + 1) * 512;
      pv0 = *(const float4*)(xp);
      pv1 = *(const float4*)(xp + 128);
      pv2 = *(const float4*)(xp + 256);
      pv3 = *(const float4*)(xp + 384);
    }

    f32x4 amA[4], amB[4], dm;
#pragma unroll
    for (int g = 0; g < 4; ++g) {
      amA[g] = (f32x4){0.f, 0.f, 0.f, 0.f};
      amB[g] = (f32x4){0.f, 0.f, 0.f, 0.f};
    }
    dm = (f32x4){0.f, 0.f, 0.f, 0.f};
#pragma unroll
    for (int kt = 0; kt < 2; ++kt) {
      const f16x8 ah0 = *(const f16x8*)&hhb[p][(kt * 64 + l) * 8];
      const f16x8 ah1 = *(const f16x8*)&hhb[p][((kt + 2) * 64 + l) * 8];
      const f16x8 cf0 = *(const f16x8*)&chb[p][(kt * 64 + l) * 8];
      const f16x8 cf1 = *(const f16x8*)&chb[p][((kt + 2) * 64 + l) * 8];
#pragma unroll
      for (int g = 0; g < 4; ++g) {
        amA[g] = __builtin_amdgcn_mfma_f32_16x16x32_f16(ah0, Bh[kt * 4 + g], amA[g], 0, 0, 0);
        amB[g] = __builtin_amdgcn_mfma_f32_16x16x32_f16(ah1, Bh[(kt + 2) * 4 + g], amB[g], 0, 0, 0);
      }
      dm = __builtin_amdgcn_mfma_f32_16x16x32_f16(cf0, Dh[kt], dm, 0, 0, 0);
      dm = __builtin_amdgcn_mfma_f32_16x16x32_f16(cf1, Dh[kt + 2], dm, 0, 0, 0);
    }

#pragma unroll
    for (int q = 0; q < 4; ++q) {
      if (t < len_q[q]) {
        const float* xr = &xut[p][(rq0 + q) * 516 + hd];
        const float tt = tsh[(rq0 + q) * 32 + t];
        const float cs1 = tanhf_(dm[q] + bdj);
        const float f  = sigf(amA[0][q] + amB[0][q] + xr[0]   + blr[0]);
        const float ii = sigf(amA[1][q] + amB[1][q] + xr[128] + blr[1]);
        const float o  = sigf(amA[2][q] + amB[2][q] + xr[256] + blr[2]);
        const float ct = sigf(amA[3][q] + amB[3][q] + xr[384] + blr[3]);
        const float c2 = f * (creg[q] + cs1 * (tt - 1.f)) + ii * ct;
        creg[q] = c2;
        hreg[q] = o * tanhf_(c2);
        oprev[q] = o;
      }
      hhb[p ^ 1][eoff0 + q * 8] = (_Float16)hreg[q];
      chb[p ^ 1][eoff0 + q * 8] = (_Float16)creg[q];
    }

    if (more) {
      *(float4*)&xut[p ^ 1][xdst]       = pv0;
      *(float4*)&xut[p ^ 1][xdst + 128] = pv1;
      *(float4*)&xut[p ^ 1][xdst + 256] = pv2;
      *(float4*)&xut[p ^ 1][xdst + 384] = pv3;
    }
    barrier_lds_only();
  }

  {
    const int tp = maxlen - 1;
#pragma unroll
    for (int q = 0; q < 4; ++q) {
      if (tp >= 0 && tp < len_q[q]) {
        outs[((size_t)(s * 160 + n_q[q]) * 30 + tp) * 128 + hd] = oprev[q];
        if (tp == len_q[q] - 1) hn[(size_t)(s * 160 + n_q[q]) * 128 + hd] = oprev[q];
      }
    }
  }
}

// ---------------------------------------------------------------------------
// K3 v7: MFMA attention-1 with LDS-staged o-tile (unchanged).
// ---------------------------------------------------------------------------
__global__ __launch_bounds__(512, 2) void k3_attn1(const _Float16* __restrict__ W1f,
                                                   const _Float16* __restrict__ W2f,
                                                   const float* __restrict__ b1,
                                                   const float* __restrict__ b2,
                                                   const float* __restrict__ V,
                                                   const float* __restrict__ outs,
                                                   const float* __restrict__ hn,
                                                   const int* __restrict__ lens,
                                                   float* __restrict__ ctx) {
  const int s = blockIdx.x;
  const int sg = blockIdx.y;
  const int tid = threadIdx.x;
  const int w = tid >> 6, l = tid & 63;
  const int nbase = s * 160 + sg * 8;

  __shared__ _Float16 osh[32768];
  __shared__ float u[16][132];
  __shared__ float red[8][8][32];
  __shared__ float score[8][32];
  __shared__ int lensh[8];

  if (tid < 8) {
    const int n = sg * 8 + tid;
    lensh[tid] = lens[((n / 5) * 8 + s) * 5 + (n % 5)];
  }

#pragma unroll
  for (int i = 0; i < 8; ++i) {
    const int c = tid + i * 512;
    const int nl = c >> 9;
    const int th = (c >> 8) & 1;
    const int kt = (c >> 6) & 3;
    const int lp = c & 63;
    const int t15 = lp & 15;
    const int kb = kt * 32 + (lp >> 4) * 8;
    const int t = th * 16 + t15;
    f16x8 v;
    if (t < 30) {
      const float* src = outs + ((size_t)(nbase + nl) * 30 + t) * 128 + kb;
      const float4 a = *(const float4*)(src);
      const float4 b = *(const float4*)(src + 4);
      v[0]=(_Float16)a.x; v[1]=(_Float16)a.y; v[2]=(_Float16)a.z; v[3]=(_Float16)a.w;
      v[4]=(_Float16)b.x; v[5]=(_Float16)b.y; v[6]=(_Float16)b.z; v[7]=(_Float16)b.w;
    } else {
      v = (f16x8){(_Float16)0.f,(_Float16)0.f,(_Float16)0.f,(_Float16)0.f,
                  (_Float16)0.f,(_Float16)0.f,(_Float16)0.f,(_Float16)0.f};
    }
    *(f16x8*)&osh[c * 8] = v;
  }

  f16x8 W1r[4], W2r[4];
  {
    const _Float16* w1b = W1f + (size_t)(s * 8 + w) * 2048 + l * 8;
    const _Float16* w2b = W2f + (size_t)(s * 8 + w) * 2048 + l * 8;
#pragma unroll
    for (int kt = 0; kt < 4; ++kt) {
      W1r[kt] = *(const f16x8*)&w1b[kt * 512];
      W2r[kt] = *(const f16x8*)&w2b[kt * 512];
    }
  }

  const int hd = w * 16 + (l & 15);
  const float Vhd = V[s * 128 + hd];
  const float b12 = b1[s * 128 + hd] + b2[s * 128 + hd];
  const int kc = (l >> 4) << 3;

  {
    const int rsrc = min(l & 15, 7);
    f32x4 dm = (f32x4){0.f, 0.f, 0.f, 0.f};
#pragma unroll
    for (int kt = 0; kt < 4; ++kt) {
      const float* hp = hn + (size_t)(nbase + rsrc) * 128 + kt * 32 + kc;
      const float4 a = *(const float4*)(hp);
      const float4 b = *(const float4*)(hp + 4);
      f16x8 ah;
      ah[0]=(_Float16)a.x; ah[1]=(_Float16)a.y; ah[2]=(_Float16)a.z; ah[3]=(_Float16)a.w;
      ah[4]=(_Float16)b.x; ah[5]=(_Float16)b.y; ah[6]=(_Float16)b.z; ah[7]=(_Float16)b.w;
      dm = __builtin_amdgcn_mfma_f32_16x16x32_f16(ah, W1r[kt], dm, 0, 0, 0);
    }
#pragma unroll
    for (int q = 0; q < 4; ++q) u[(l >> 4) * 4 + q][hd] = dm[q] + b12;
  }
  __syncthreads();

#pragma unroll
  for (int m = 0; m < 16; ++m) {
    const int nl = m >> 1, th = m & 1;
    const int cbase = ((nl * 2 + th) * 4) * 64;
    f32x4 acc = (f32x4){0.f, 0.f, 0.f, 0.f};
#pragma unroll
    for (int kt = 0; kt < 4; ++kt) {
      const f16x8 ah = *(const f16x8*)&osh[(cbase + kt * 64 + l) * 8];
      acc = __builtin_amdgcn_mfma_f32_16x16x32_f16(ah, W2r[kt], acc, 0, 0, 0);
    }
    const float uv = u[nl][hd];
#pragma unroll
    for (int q = 0; q < 4; ++q) {
      float p = tanhf_(acc[q] + uv) * Vhd;
      p += __shfl_xor(p, 1);
      p += __shfl_xor(p, 2);
      p += __shfl_xor(p, 4);
      p += __shfl_xor(p, 8);
      const int t = th * 16 + (l >> 4) * 4 + q;
      if ((l & 15) == 0 && t < 30) red[w][nl][t] = p;
    }
  }
  __syncthreads();

  if (tid < 256) {
    const int nl = tid >> 5, t = tid & 31;
    if (t < 30) {
      float sc = 0.f;
#pragma unroll
      for (int ww = 0; ww < 8; ++ww) sc += red[ww][nl][t];
      score[nl][t] = sc;
    }
  }
  __syncthreads();

  {
    const int nl = tid >> 6, jg = tid & 63;
    const int len = lensh[nl];
    float mx = -1e30f;
    for (int t = 0; t < len; ++t) mx = fmaxf(mx, score[nl][t]);
    const float* ob = outs + (size_t)(nbase + nl) * 30 * 128 + jg * 2;
    float sum = 0.f;
    float cx0 = 0.f, cx1 = 0.f;
    for (int t = 0; t < len; ++t) {
      const float e = __expf(score[nl][t] - mx);
      sum += e;
      const float2 o2 = *(const float2*)(ob + (size_t)t * 128);
      cx0 += e * o2.x; cx1 += e * o2.y;
    }
    const float r = rcp_(sum);
    float2 res = {cx0 * r, cx1 * r};
    *(float2*)&ctx[(size_t)(nbase + nl) * 128 + jg * 2] = res;
  }
}

// ---------------------------------------------------------------------------
// K45: FUSED lstm2 + attention2 + output MLP (unchanged).
// ---------------------------------------------------------------------------
__global__ __launch_bounds__(512, 2) void k45_fused(const float* __restrict__ Wih,
                                                    const float* __restrict__ bih,
                                                    const float* __restrict__ Whh,
                                                    const float* __restrict__ bhh,
                                                    const float* __restrict__ aW1,
                                                    const float* __restrict__ ab1,
                                                    const float* __restrict__ aW2,
                                                    const float* __restrict__ ab2,
                                                    const float* __restrict__ aV,
                                                    const float* __restrict__ x1W,
                                                    const float* __restrict__ x1b,
                                                    const float* __restrict__ x2W,
                                                    const float* __restrict__ x2b,
                                                    const float* __restrict__ ctx,
                                                    float* __restrict__ y) {
  const int s = blockIdx.y, b = blockIdx.x;
  const int tid = threadIdx.x;
  __shared__ float xs[5][128];
  __shared__ float hsm[5][128];
  __shared__ float hcur[128];
  __shared__ float gsh[512];
  __shared__ float red[4][128];
  __shared__ float wred[2];
  __shared__ float sc[5];
  __shared__ float u_sh[128];
  __shared__ float cs2[128];
  __shared__ float t1[128];
  __shared__ float red2[8][64];

  for (int idx = tid; idx < 640; idx += 512)
    (&xs[0][0])[idx] = ctx[(size_t)(s * 160 + b * 5) * 128 + idx];
  if (tid < 128) hcur[tid] = 0.f;
  __syncthreads();

  const float* Wis = Wih + (size_t)s * 65536;
  const float* Whs = Whh + (size_t)s * 65536;
  const float bias = bih[s * 512 + tid] + bhh[s * 512 + tid];
  float xw[5] = {bias, bias, bias, bias, bias};
  float whh[128];
#pragma unroll
  for (int k = 0; k < 128; ++k) {
    const float wi = Wis[k * 512 + tid];
    whh[k] = Whs[k * 512 + tid];
#pragma unroll
    for (int dd = 0; dd < 5; ++dd) xw[dd] += xs[dd][k] * wi;
  }

  float c = 0.f;
  for (int dd = 0; dd < 5; ++dd) {
    float g = xw[dd];
#pragma unroll
    for (int k = 0; k < 128; ++k) g += hcur[k] * whh[k];
    gsh[tid] = g;
    __syncthreads();
    if (tid < 128) {
      const int j = tid;
      const float c2 = sigf(gsh[128 + j]) * c + sigf(gsh[j]) * tanhf_(gsh[256 + j]);
      const float h2 = sigf(gsh[384 + j]) * tanhf_(c2);
      c = c2;
      hcur[j] = h2;
      hsm[dd][j] = h2;
    }
    __syncthreads();
  }

  const int q = tid >> 7, j = tid & 127;
  const float* W1s = aW1 + (size_t)s * 16384;
  const float* W2s = aW2 + (size_t)s * 16384;

  {
    float part = 0.f;
#pragma unroll
    for (int k = 0; k < 32; ++k) part += hsm[4][q * 32 + k] * W1s[(q * 32 + k) * 128 + j];
    red[q][j] = part;
  }
  __syncthreads();
  if (tid < 128)
    u_sh[j] = red[0][j] + red[1][j] + red[2][j] + red[3][j] +
              ab1[s * 128 + j] + ab2[s * 128 + j];
  __syncthreads();

  for (int d = 0; d < 5; ++d) {
    float part = 0.f;
#pragma unroll
    for (int k = 0; k < 32; ++k) part += hsm[d][q * 32 + k] * W2s[(q * 32 + k) * 128 + j];
    red[q][j] = part;
    __syncthreads();
    if (tid < 128) {
      float a = u_sh[j] + red[0][j] + red[1][j] + red[2][j] + red[3][j];
      float pv = tanhf_(a) * aV[s * 128 + j];
#pragma unroll
      for (int off = 32; off; off >>= 1) pv += __shfl_down(pv, off);
      if ((tid & 63) == 0) wred[tid >> 6] = pv;
    }
    __syncthreads();
    if (tid == 0) sc[d] = wred[0] + wred[1];
    __syncthreads();
  }

  if (tid < 128) {
    float m = sc[0];
#pragma unroll
    for (int d = 1; d < 5; ++d) m = fmaxf(m, sc[d]);
    float e[5], sum = 0.f;
#pragma unroll
    for (int d = 0; d < 5; ++d) { e[d] = __expf(sc[d] - m); sum += e[d]; }
    float cx = 0.f;
#pragma unroll
    for (int d = 0; d < 5; ++d) cx += e[d] * hsm[d][j];
    cs2[j] = cx * rcp_(sum);
  }
  __syncthreads();

  {
    float part = 0.f;
#pragma unroll
    for (int k = 0; k < 32; ++k) part += cs2[q * 32 + k] * x1W[(size_t)s * 16384 + (q * 32 + k) * 128 + j];
    red[q][j] = part;
  }
  __syncthreads();
  if (tid < 128)
    t1[j] = fmaxf(red[0][j] + red[1][j] + red[2][j] + red[3][j] + x1b[s * 128 + j], 0.f);
  __syncthreads();

  {
    const int q2 = tid >> 6, j2 = tid & 63;
    float part = 0.f;
#pragma unroll
    for (int k = 0; k < 16; ++k) part += t1[q2 * 16 + k] * x2W[(size_t)s * 8192 + (q2 * 16 + k) * 64 + j2];
    red2[q2][j2] = part;
  }
  __syncthreads();
  if (tid < 64) {
    float yy = x2b[s * 64 + tid];
#pragma unroll
    for (int g = 0; g < 8; ++g) yy += red2[g][tid];
    y[(size_t)(s * 32 + b) * 64 + tid] = yy;
  }
}

// ---------------------------------------------------------------------------
// K6: final combine (unchanged).
// ---------------------------------------------------------------------------
__global__ __launch_bounds__(256) void k6_final(const float* __restrict__ stock,
                                                const float* __restrict__ h1W,
                                                const float* __restrict__ h1b,
                                                const float* __restrict__ h2W,
                                                const float* __restrict__ h2b,
                                                const float* __restrict__ hcW,
                                                const float* __restrict__ hcb,
                                                const float* __restrict__ yws,
                                                float* __restrict__ out) {
  const int tid = threadIdx.x;
  __shared__ float sf[32 * 17];
  __shared__ float hid[32 * 64];
  __shared__ float xs[32 * 32];
  for (int idx = tid; idx < 544; idx += 256) sf[idx] = stock[idx];
  __syncthreads();
  for (int idx = tid; idx < 2048; idx += 256) {
    const int b = idx >> 6, k = idx & 63;
    float a = h1b[k];
    for (int q = 0; q < 17; ++q) a += sf[b * 17 + q] * h1W[q * 64 + k];
    hid[idx] = fmaxf(a, 0.f);
  }
  __syncthreads();
  for (int idx = tid; idx < 1024; idx += 256) {
    const int b = idx >> 5, mm = idx & 31;
    float a = h2b[mm];
    for (int k = 0; k < 64; ++k) a += hid[b * 64 + k] * h2W[k * 32 + mm];
    xs[idx] = a;
  }
  __syncthreads();
  {
    const int b = tid >> 3, o = tid & 7;
    float a = hcb[o];
    for (int c = 0; c < 32; ++c) a += xs[b * 32 + c] * hcW[c * 8 + o];
    for (int c = 32; c < 544; ++c) {
      const int ss = (c - 32) >> 6, k = (c - 32) & 63;
      a += yws[((size_t)ss * 32 + b) * 64 + k] * hcW[c * 8 + o];
    }
    out[tid] = tanhf_(a);
  }
}

// ---------------------------------------------------------------------------
extern "C" void kernel_launch(void* const* d_in, const int* in_sizes, int n_in,
                              void* d_out, int out_size, void* d_ws, size_t ws_size,
                              hipStream_t stream) {
  (void)in_sizes; (void)n_in; (void)out_size; (void)ws_size;
  const float* stock = (const float*)d_in[0];
  const float* sent  = (const float*)d_in[1];
  const float* times = (const float*)d_in[2];
  const int*   lens  = (const int*)d_in[3];
  const float* tlWall = (const float*)d_in[4];
  const float* tlball = (const float*)d_in[5];
  const float* tlUall = (const float*)d_in[6];
  const float* tlbU   = (const float*)d_in[7];
  const float* tlWd   = (const float*)d_in[8];
  const float* tlbd   = (const float*)d_in[9];
  const float* a1W1 = (const float*)d_in[10];
  const float* a1b1 = (const float*)d_in[11];
  const float* a1W2 = (const float*)d_in[12];
  const float* a1b2 = (const float*)d_in[13];
  const float* a1V  = (const float*)d_in[14];
  const float* a1bV = (const float*)d_in[15];
  const float* l2Wih = (const float*)d_in[16];
  const float* l2bih = (const float*)d_in[17];
  const float* l2Whh = (const float*)d_in[18];
  const float* l2bhh = (const float*)d_in[19];
  const float* a2W1 = (const float*)d_in[20];
  const float* a2b1 = (const float*)d_in[21];
  const float* a2W2 = (const float*)d_in[22];
  const float* a2b2 = (const float*)d_in[23];
  const float* a2V  = (const float*)d_in[24];
  const float* a2bV = (const float*)d_in[25];
  const float* x1W  = (const float*)d_in[26];
  const float* x1b  = (const float*)d_in[27];
  const float* x2W  = (const float*)d_in[28];
  const float* x2b  = (const float*)d_in[29];
  const float* h1W  = (const float*)d_in[30];
  const float* h1b  = (const float*)d_in[31];
  const float* h2W  = (const float*)d_in[32];
  const float* h2b  = (const float*)d_in[33];
  const float* hcW  = (const float*)d_in[34];
  const float* hcb  = (const float*)d_in[35];
  (void)a1bV; (void)a2bV;

  float* ws = (float*)d_ws;
  float* XU    = ws;               // 8*160*30*512   = 19,660,800
  float* outs  = XU + 19660800;    // 8*160*30*128   =  4,915,200
  float* hnb   = outs + 4915200;   // 8*160*128      =    163,840
  float* ctx   = hnb + 163840;     // 8*160*128      =    163,840
  float* yb    = ctx + 163840;     // 8*32*64        =     16,384
  _Float16* Uhw = (_Float16*)(yb + 16384);    // 8*512*768 halfs
  _Float16* Wfh = Uhw + 8 * 512 * 768;        // 8*8*8192 halfs
  _Float16* Dfh = Wfh + 8 * 8 * 8192;         // 8*8*2048 halfs
  _Float16* W1f = Dfh + 8 * 8 * 2048;         // 8*8*2048 halfs
  _Float16* W2f = W1f + 8 * 8 * 2048;         // 8*8*2048 halfs
  int* rowmap = (int*)(W2f + 8 * 8 * 2048);   // 8*4800 ints
  int* Msd    = rowmap + 8 * 4800;            // 8 ints

  k0_rowmap<<<8, 256, 0, stream>>>(lens, rowmap, Msd);
  k0_usplit<<<dim3(12, 8, 8), 256, 0, stream>>>(tlUall, Uhw);
  k0_wprep<<<dim3(8, 8), 256, 0, stream>>>(tlWall, tlWd, Wfh, Dfh);
  k0_aprep<<<dim3(8, 8), 256, 0, stream>>>(a1W1, a1W2, W1f, W2f);
  k1_xu<<<dim3(8, 152), 256, 0, stream>>>(sent, Uhw, tlbU, rowmap, Msd, XU);
  k2_tlstm<<<dim3(8, 10), 512, 0, stream>>>(Wfh, Dfh, tlball, tlbd, XU, times, lens, outs, hnb);
  k3_attn1<<<dim3(8, 20), 512, 0, stream>>>(W1f, W2f, a1b1, a1b2, a1V, outs, hnb, lens, ctx);
  k45_fused<<<dim3(32, 8), 512, 0, stream>>>(l2Wih, l2bih, l2Whh, l2bhh,
                                             a2W1, a2b1, a2W2, a2b2, a2V,
                                             x1W, x1b, x2W, x2b, ctx, yb);
  k6_final<<<1, 256, 0, stream>>>(stock, h1W, h1b, h2W, h2b, hcW, hcb, yb, (float*)d_out);
}

// Round 20
// 200.998 us; speedup vs baseline: 1.4003x; 1.0171x over previous
//
#include <hip/hip_runtime.h>
#include <cstddef>

// Problem constants: S=8, B=32, D=5, T=30, E=768, H=128, 4H=512.

typedef __attribute__((ext_vector_type(8))) _Float16 f16x8;
typedef __attribute__((ext_vector_type(4))) _Float16 f16x4;
typedef __attribute__((ext_vector_type(2))) _Float16 f16x2;
typedef __attribute__((ext_vector_type(4))) float f32x4;

__device__ __forceinline__ float rcp_(float x) { return __builtin_amdgcn_rcpf(x); }
__device__ __forceinline__ float sigf(float x) { return rcp_(1.0f + __expf(-x)); }
__device__ __forceinline__ float tanhf_(float x) { return 1.0f - 2.0f * rcp_(__expf(2.0f * x) + 1.0f); }

// LDS-only barrier: drains lgkmcnt but NOT vmcnt (global ops stay in flight).
__device__ __forceinline__ void barrier_lds_only() {
  asm volatile("s_waitcnt lgkmcnt(0)" ::: "memory");
  __builtin_amdgcn_s_barrier();
  __builtin_amdgcn_sched_barrier(0);
}

// ---------------------------------------------------------------------------
// K0r: per-stock compacted row map: rows (n,t) with t < len[s,n].
// ---------------------------------------------------------------------------
__global__ __launch_bounds__(256) void k0_rowmap(const int* __restrict__ lens,
                                                 int* __restrict__ rowmap,
                                                 int* __restrict__ Ms) {
  const int s = blockIdx.x;
  const int tid = threadIdx.x;
  __shared__ int st[160];
  __shared__ int ln[160];
  if (tid < 160) {
    const int b = tid / 5, d = tid % 5;
    ln[tid] = lens[(b * 8 + s) * 5 + d];
  }
  __syncthreads();
  if (tid == 0) {
    int run = 0;
    for (int n = 0; n < 160; ++n) { st[n] = run; run += ln[n]; }
    Ms[s] = run;
  }
  __syncthreads();
  if (tid < 160) {
    const int base = st[tid], l = ln[tid];
    for (int t = 0; t < l; ++t) rowmap[s * 4800 + base + t] = tid * 30 + t;
  }
}

// ---------------------------------------------------------------------------
// K0: transpose U to fp16 (hi only) via LDS tiles (for k1).
// ---------------------------------------------------------------------------
__global__ __launch_bounds__(256) void k0_usplit(const float* __restrict__ U,
                                                 _Float16* __restrict__ Uh) {
  const int s = blockIdx.z;
  const int k0 = blockIdx.x * 64;
  const int n0 = blockIdx.y * 64;
  const int tid = threadIdx.x;
  __shared__ _Float16 Th[64 * 66];
  const float* Us = U + (size_t)s * 768 * 512;
#pragma unroll
  for (int rep = 0; rep < 16; ++rep) {
    const int idx = rep * 256 + tid;
    const int r = idx >> 6, c = idx & 63;
    Th[r * 66 + c] = (_Float16)Us[(size_t)(k0 + r) * 512 + n0 + c];
  }
  __syncthreads();
  _Float16* uhs = Uh + (size_t)s * 512 * 768;
#pragma unroll
  for (int rep = 0; rep < 8; ++rep) {
    const int idx = rep * 256 + tid;
    const int nn = idx >> 5;
    const int kp = (idx & 31) * 2;
    const f16x2 h2 = {Th[kp * 66 + nn], Th[(kp + 1) * 66 + nn]};
    *(f16x2*)&uhs[(size_t)(n0 + nn) * 768 + k0 + kp] = h2;
  }
}

// ---------------------------------------------------------------------------
// K0w: pack Wall (hi only) and Wd (hi) into MFMA B-fragment-linear layout.
// ---------------------------------------------------------------------------
__global__ __launch_bounds__(256) void k0_wprep(const float* __restrict__ Wall,
                                                const float* __restrict__ Wd,
                                                _Float16* __restrict__ Wfh,
                                                _Float16* __restrict__ Dfh) {
  const int w = blockIdx.x, s = blockIdx.y;
  const int tid = threadIdx.x;
  const float* Ws = Wall + (size_t)s * 65536;
  _Float16* oh = Wfh + (size_t)(s * 8 + w) * 8192;
  for (int c = tid; c < 1024; c += 256) {
    const int kt = c >> 8, nt = (c >> 6) & 3, l = c & 63;
    const int n = nt * 128 + w * 16 + (l & 15);   // gate-major per wave
    const int kb = kt * 32 + ((l >> 4) << 3);
    f16x8 hv;
#pragma unroll
    for (int e = 0; e < 8; ++e) hv[e] = (_Float16)Ws[(size_t)(kb + e) * 512 + n];
    *(f16x8*)&oh[c * 8] = hv;
  }
  {
    const float* Ds = Wd + (size_t)s * 16384;
    _Float16* od = Dfh + (size_t)(s * 8 + w) * 2048;
    const int c = tid;
    const int kt = c >> 6, l = c & 63;
    const int n = w * 16 + (l & 15);
    const int kb = kt * 32 + ((l >> 4) << 3);
    f16x8 hv;
#pragma unroll
    for (int e = 0; e < 8; ++e) hv[e] = (_Float16)Ds[(size_t)(kb + e) * 128 + n];
    *(f16x8*)&od[c * 8] = hv;
  }
}

// ---------------------------------------------------------------------------
// K0a: pack a1_W1 and a1_W2 into per-wave 16-col B-frag layout.
// ---------------------------------------------------------------------------
__global__ __launch_bounds__(256) void k0_aprep(const float* __restrict__ W1,
                                                const float* __restrict__ W2,
                                                _Float16* __restrict__ W1f,
                                                _Float16* __restrict__ W2f) {
  const int w = blockIdx.x, s = blockIdx.y;
  const int c = threadIdx.x;          // 0..255 = kt*64 + l
  const int kt = c >> 6, l = c & 63;
  const int n = w * 16 + (l & 15);
  const int kb = kt * 32 + ((l >> 4) << 3);
  const float* W1s = W1 + (size_t)s * 16384;
  const float* W2s = W2 + (size_t)s * 16384;
  f16x8 v1, v2;
#pragma unroll
  for (int e = 0; e < 8; ++e) {
    v1[e] = (_Float16)W1s[(size_t)(kb + e) * 128 + n];
    v2[e] = (_Float16)W2s[(size_t)(kb + e) * 128 + n];
  }
  *(f16x8*)&W1f[(size_t)(s * 8 + w) * 2048 + c * 8] = v1;
  *(f16x8*)&W2f[(size_t)(s * 8 + w) * 2048 + c * 8] = v2;
}

// ---------------------------------------------------------------------------
// K1 v7: M-tile 64 (was 128) -> ~2x blocks/CU for chain interleaving.
//   4 waves = 4 N-quadrants of 32 cols; acc[4][2]; 8 MFMA/step; 24KB LDS.
//   Same XOR swizzle, same LDS-only barrier, same single fp16 product.
// ---------------------------------------------------------------------------
__global__ __launch_bounds__(256, 4) void k1_xu(const float* __restrict__ sent,
                                                const _Float16* __restrict__ Uh,
                                                const float* __restrict__ bU,
                                                const int* __restrict__ rowmap,
                                                const int* __restrict__ Ms,
                                                float* __restrict__ XU) {
  const int s = blockIdx.x;
  const int M = Ms[s];
  const int nt = blockIdx.y & 3;
  const int mt = blockIdx.y >> 2;        // 0..74
  if (mt * 64 >= M) return;
  const int tid = threadIdx.x;
  const int lane = tid & 63;
  const int w = tid >> 6;                // N-quadrant 0..3 (cols w*32..w*32+32)

  __shared__ _Float16 Al[2][64 * 32];
  __shared__ _Float16 Bh[2][128 * 32];

  const int ar1 = tid >> 2;              // staging row 0..63
  const int chk = tid & 3;
  const int afk = chk * 8;
  const int fw = (ar1 ^ (ar1 >> 2)) & 3; // same key for ar1 and ar1+64
  const int wA1 = ar1 * 32 + ((chk ^ fw) * 8);
  const int wA2 = wA1 + 64 * 32;

  const int* rms = rowmap + s * 4800;
  const float* asrc1;
  {
    int i1 = mt * 64 + ar1; if (i1 > M - 1) i1 = M - 1;
    const int grow = rms[i1];
    const int nn = grow / 30, tt = grow % 30, ab = nn / 5, ad = nn % 5;
    asrc1 = sent + (size_t)((((ab * 8 + s) * 5 + ad) * 30) + tt) * 768 + afk;
  }
  const _Float16* UhS = Uh + (size_t)s * 512 * 768;
  const _Float16* bh1 = UhS + (size_t)(nt * 128 + ar1) * 768 + afk;
  const _Float16* bh2 = UhS + (size_t)(nt * 128 + ar1 + 64) * 768 + afk;

  const int q = lane >> 4;
  const int l15 = lane & 15;
  int aoff[4], boff[2];
#pragma unroll
  for (int f = 0; f < 4; ++f) {
    const int row = f * 16 + l15;
    const int fr = (row ^ (row >> 2)) & 3;
    aoff[f] = row * 32 + ((q ^ fr) * 8);
  }
#pragma unroll
  for (int f = 0; f < 2; ++f) {
    const int row = w * 32 + f * 16 + l15;
    const int fr = (row ^ (row >> 2)) & 3;
    boff[f] = row * 32 + ((q ^ fr) * 8);
  }

  f32x4 acc[4][2];
#pragma unroll
  for (int i = 0; i < 4; ++i)
#pragma unroll
    for (int j = 0; j < 2; ++j) acc[i][j] = (f32x4){0.f, 0.f, 0.f, 0.f};

  // prologue: stage ks=0 into buf 0
  {
    const float4 a1a = *(const float4*)(asrc1);
    const float4 a1b = *(const float4*)(asrc1 + 4);
    const f16x8 vh1 = *(const f16x8*)(bh1);
    const f16x8 vh2 = *(const f16x8*)(bh2);
    f16x8 h1;
    h1[0]=(_Float16)a1a.x; h1[1]=(_Float16)a1a.y; h1[2]=(_Float16)a1a.z; h1[3]=(_Float16)a1a.w;
    h1[4]=(_Float16)a1b.x; h1[5]=(_Float16)a1b.y; h1[6]=(_Float16)a1b.z; h1[7]=(_Float16)a1b.w;
    *(f16x8*)&Al[0][wA1] = h1;
    *(f16x8*)&Bh[0][wA1] = vh1;
    *(f16x8*)&Bh[0][wA2] = vh2;
  }
  __syncthreads();

  int cur = 0;
  for (int ks = 0; ks < 24; ++ks) {
    const int nxt = cur ^ 1;
    const bool more = (ks < 23);
    float4 a1a, a1b;
    f16x8 vh1, vh2;
    if (more) {
      const int ko = (ks + 1) * 32;
      a1a = *(const float4*)(asrc1 + ko);
      a1b = *(const float4*)(asrc1 + ko + 4);
      vh1 = *(const f16x8*)(bh1 + ko);
      vh2 = *(const f16x8*)(bh2 + ko);
    }
    {
      const _Float16* Ab = &Al[cur][0];
      const _Float16* Bhb = &Bh[cur][0];
      f16x8 af[4], bhf[2];
#pragma unroll
      for (int fm = 0; fm < 4; ++fm) af[fm] = *(const f16x8*)&Ab[aoff[fm]];
#pragma unroll
      for (int fn = 0; fn < 2; ++fn) bhf[fn] = *(const f16x8*)&Bhb[boff[fn]];
#pragma unroll
      for (int fm = 0; fm < 4; ++fm)
#pragma unroll
        for (int fn = 0; fn < 2; ++fn)
          acc[fm][fn] = __builtin_amdgcn_mfma_f32_16x16x32_f16(af[fm], bhf[fn], acc[fm][fn], 0, 0, 0);
    }
    if (more) {
      f16x8 h1;
      h1[0]=(_Float16)a1a.x; h1[1]=(_Float16)a1a.y; h1[2]=(_Float16)a1a.z; h1[3]=(_Float16)a1a.w;
      h1[4]=(_Float16)a1b.x; h1[5]=(_Float16)a1b.y; h1[6]=(_Float16)a1b.z; h1[7]=(_Float16)a1b.w;
      *(f16x8*)&Al[nxt][wA1] = h1;
      *(f16x8*)&Bh[nxt][wA1] = vh1;
      *(f16x8*)&Bh[nxt][wA2] = vh2;
    }
    barrier_lds_only();
    cur = nxt;
  }

  const int lq = lane >> 4;
  const int colbase = nt * 128 + w * 32;
  const int ibase = mt * 64;
  float* XUs = XU + (size_t)s * 4800 * 512;
  int rowm[4][4];
#pragma unroll
  for (int fm = 0; fm < 4; ++fm)
#pragma unroll
    for (int r = 0; r < 4; ++r) {
      const int i = ibase + fm * 16 + lq * 4 + r;
      rowm[fm][r] = (i < M) ? rms[i] : -1;
    }
#pragma unroll
  for (int fn = 0; fn < 2; ++fn) {
    const int col = colbase + fn * 16 + l15;
    const float bias = bU[s * 512 + col];
#pragma unroll
    for (int fm = 0; fm < 4; ++fm)
#pragma unroll
      for (int r = 0; r < 4; ++r) {
        const int row = rowm[fm][r];
        if (row >= 0) XUs[(size_t)row * 512 + col] = acc[fm][fn][r] + bias;
      }
  }
}

// ---------------------------------------------------------------------------
// K2 v9: MFMA time-LSTM (unchanged).
// ---------------------------------------------------------------------------
__global__ __launch_bounds__(512, 2) void k2_tlstm(const _Float16* __restrict__ Wfh,
                                                   const _Float16* __restrict__ Dfh,
                                                   const float* __restrict__ ball,
                                                   const float* __restrict__ bd,
                                                   const float* __restrict__ XU,
                                                   const float* __restrict__ times,
                                                   const int* __restrict__ lens,
                                                   float* __restrict__ outs,
                                                   float* __restrict__ hn) {
  const int s = blockIdx.x;
  const int mg = blockIdx.y;
  const int tid = threadIdx.x;
  const int w = tid >> 6, l = tid & 63;

  __shared__ _Float16 hhb[2][2048];
  __shared__ _Float16 chb[2][2048];
  __shared__ float xut[2][16 * 516];
  __shared__ float tsh[16 * 32];
  __shared__ int lensh[16];

  if (tid < 16) {
    const int n = mg * 16 + tid;
    lensh[tid] = lens[((n / 5) * 8 + s) * 5 + (n % 5)];
  }
  if (tid < 480) {
    const int r = tid / 30, c = tid % 30;
    const int n = mg * 16 + r;
    tsh[r * 32 + c] = times[(((n / 5) * 8 + s) * 5 + (n % 5)) * 30 + c];
  }

  f16x8 Bh[16], Dh[4];
  {
    const _Float16* wb = Wfh + (size_t)(s * 8 + w) * 8192 + l * 8;
    const _Float16* db = Dfh + (size_t)(s * 8 + w) * 2048 + l * 8;
#pragma unroll
    for (int c = 0; c < 16; ++c) Bh[c] = *(const f16x8*)&wb[c * 512];
#pragma unroll
    for (int c = 0; c < 4; ++c) Dh[c] = *(const f16x8*)&db[c * 512];
  }

  const int hd = w * 16 + (l & 15);
  const int rq0 = (l >> 4) * 4;
  const int lp0 = rq0 | (((hd >> 3) & 3) << 4);
  const int eoff0 = ((hd >> 5) * 64 + lp0) * 8 + (hd & 7);

#pragma unroll
  for (int q = 0; q < 4; ++q) {
    hhb[0][eoff0 + q * 8] = (_Float16)0.f;
    chb[0][eoff0 + q * 8] = (_Float16)0.f;
  }

  int n_q[4];
#pragma unroll
  for (int q = 0; q < 4; ++q) n_q[q] = mg * 16 + rq0 + q;
  float blr[4];
#pragma unroll
  for (int g = 0; g < 4; ++g) blr[g] = ball[s * 512 + g * 128 + hd];
  const float bdj = bd[s * 128 + hd];

  const int sr = tid >> 5;
  const int sc = tid & 31;
  const float* xsrc = XU + (size_t)(s * 160 + mg * 16 + sr) * 30 * 512 + sc * 4;
  const int xdst = sr * 516 + sc * 4;

  __syncthreads();

  int len_q[4];
  int maxlen = 0;
#pragma unroll
  for (int i = 0; i < 16; ++i) maxlen = max(maxlen, lensh[i]);
#pragma unroll
  for (int q = 0; q < 4; ++q) len_q[q] = lensh[rq0 + q];

  float creg[4] = {0.f, 0.f, 0.f, 0.f};
  float hreg[4] = {0.f, 0.f, 0.f, 0.f};
  float oprev[4] = {0.f, 0.f, 0.f, 0.f};

  {
    float4 v0 = *(const float4*)(xsrc);
    float4 v1 = *(const float4*)(xsrc + 128);
    float4 v2 = *(const float4*)(xsrc + 256);
    float4 v3 = *(const float4*)(xsrc + 384);
    *(float4*)&xut[0][xdst]       = v0;
    *(float4*)&xut[0][xdst + 128] = v1;
    *(float4*)&xut[0][xdst + 256] = v2;
    *(float4*)&xut[0][xdst + 384] = v3;
  }
  __syncthreads();

  for (int t = 0; t < maxlen; ++t) {
    const int p = t & 1;

    if (t > 0) {
      const int tp = t - 1;
#pragma unroll
      for (int q = 0; q < 4; ++q) {
        if (tp < len_q[q]) {
          outs[((size_t)(s * 160 + n_q[q]) * 30 + tp) * 128 + hd] = oprev[q];
          if (tp == len_q[q] - 1) hn[(size_t)(s * 160 + n_q[q]) * 128 + hd] = oprev[q];
        }
      }
    }

    float4 pv0, pv1, pv2, pv3;
    const bool more = (t + 1 < maxlen);
    if (more) {
      const float* xp = xsrc + (size_t)(t + 1) * 512;
      pv0 = *(const float4*)(xp);
      pv1 = *(const float4*)(xp + 128);
      pv2 = *(const float4*)(xp + 256);
      pv3 = *(const float4*)(xp + 384);
    }

    f32x4 amA[4], amB[4], dm;
#pragma unroll
    for (int g = 0; g < 4; ++g) {
      amA[g] = (f32x4){0.f, 0.f, 0.f, 0.f};
      amB[g] = (f32x4){0.f, 0.f, 0.f, 0.f};
    }
    dm = (f32x4){0.f, 0.f, 0.f, 0.f};
#pragma unroll
    for (int kt = 0; kt < 2; ++kt) {
      const f16x8 ah0 = *(const f16x8*)&hhb[p][(kt * 64 + l) * 8];
      const f16x8 ah1 = *(const f16x8*)&hhb[p][((kt + 2) * 64 + l) * 8];
      const f16x8 cf0 = *(const f16x8*)&chb[p][(kt * 64 + l) * 8];
      const f16x8 cf1 = *(const f16x8*)&chb[p][((kt + 2) * 64 + l) * 8];
#pragma unroll
      for (int g = 0; g < 4; ++g) {
        amA[g] = __builtin_amdgcn_mfma_f32_16x16x32_f16(ah0, Bh[kt * 4 + g], amA[g], 0, 0, 0);
        amB[g] = __builtin_amdgcn_mfma_f32_16x16x32_f16(ah1, Bh[(kt + 2) * 4 + g], amB[g], 0, 0, 0);
      }
      dm = __builtin_amdgcn_mfma_f32_16x16x32_f16(cf0, Dh[kt], dm, 0, 0, 0);
      dm = __builtin_amdgcn_mfma_f32_16x16x32_f16(cf1, Dh[kt + 2], dm, 0, 0, 0);
    }

#pragma unroll
    for (int q = 0; q < 4; ++q) {
      if (t < len_q[q]) {
        const float* xr = &xut[p][(rq0 + q) * 516 + hd];
        const float tt = tsh[(rq0 + q) * 32 + t];
        const float cs1 = tanhf_(dm[q] + bdj);
        const float f  = sigf(amA[0][q] + amB[0][q] + xr[0]   + blr[0]);
        const float ii = sigf(amA[1][q] + amB[1][q] + xr[128] + blr[1]);
        const float o  = sigf(amA[2][q] + amB[2][q] + xr[256] + blr[2]);
        const float ct = sigf(amA[3][q] + amB[3][q] + xr[384] + blr[3]);
        const float c2 = f * (creg[q] + cs1 * (tt - 1.f)) + ii * ct;
        creg[q] = c2;
        hreg[q] = o * tanhf_(c2);
        oprev[q] = o;
      }
      hhb[p ^ 1][eoff0 + q * 8] = (_Float16)hreg[q];
      chb[p ^ 1][eoff0 + q * 8] = (_Float16)creg[q];
    }

    if (more) {
      *(float4*)&xut[p ^ 1][xdst]       = pv0;
      *(float4*)&xut[p ^ 1][xdst + 128] = pv1;
      *(float4*)&xut[p ^ 1][xdst + 256] = pv2;
      *(float4*)&xut[p ^ 1][xdst + 384] = pv3;
    }
    barrier_lds_only();
  }

  {
    const int tp = maxlen - 1;
#pragma unroll
    for (int q = 0; q < 4; ++q) {
      if (tp >= 0 && tp < len_q[q]) {
        outs[((size_t)(s * 160 + n_q[q]) * 30 + tp) * 128 + hd] = oprev[q];
        if (tp == len_q[q] - 1) hn[(size_t)(s * 160 + n_q[q]) * 128 + hd] = oprev[q];
      }
    }
  }
}

// ---------------------------------------------------------------------------
// K3 v7: MFMA attention-1 with LDS-staged o-tile (unchanged).
// ---------------------------------------------------------------------------
__global__ __launch_bounds__(512, 2) void k3_attn1(const _Float16* __restrict__ W1f,
                                                   const _Float16* __restrict__ W2f,
                                                   const float* __restrict__ b1,
                                                   const float* __restrict__ b2,
                                                   const float* __restrict__ V,
                                                   const float* __restrict__ outs,
                                                   const float* __restrict__ hn,
                                                   const int* __restrict__ lens,
                                                   float* __restrict__ ctx) {
  const int s = blockIdx.x;
  const int sg = blockIdx.y;
  const int tid = threadIdx.x;
  const int w = tid >> 6, l = tid & 63;
  const int nbase = s * 160 + sg * 8;

  __shared__ _Float16 osh[32768];
  __shared__ float u[16][132];
  __shared__ float red[8][8][32];
  __shared__ float score[8][32];
  __shared__ int lensh[8];

  if (tid < 8) {
    const int n = sg * 8 + tid;
    lensh[tid] = lens[((n / 5) * 8 + s) * 5 + (n % 5)];
  }

#pragma unroll
  for (int i = 0; i < 8; ++i) {
    const int c = tid + i * 512;
    const int nl = c >> 9;
    const int th = (c >> 8) & 1;
    const int kt = (c >> 6) & 3;
    const int lp = c & 63;
    const int t15 = lp & 15;
    const int kb = kt * 32 + (lp >> 4) * 8;
    const int t = th * 16 + t15;
    f16x8 v;
    if (t < 30) {
      const float* src = outs + ((size_t)(nbase + nl) * 30 + t) * 128 + kb;
      const float4 a = *(const float4*)(src);
      const float4 b = *(const float4*)(src + 4);
      v[0]=(_Float16)a.x; v[1]=(_Float16)a.y; v[2]=(_Float16)a.z; v[3]=(_Float16)a.w;
      v[4]=(_Float16)b.x; v[5]=(_Float16)b.y; v[6]=(_Float16)b.z; v[7]=(_Float16)b.w;
    } else {
      v = (f16x8){(_Float16)0.f,(_Float16)0.f,(_Float16)0.f,(_Float16)0.f,
                  (_Float16)0.f,(_Float16)0.f,(_Float16)0.f,(_Float16)0.f};
    }
    *(f16x8*)&osh[c * 8] = v;
  }

  f16x8 W1r[4], W2r[4];
  {
    const _Float16* w1b = W1f + (size_t)(s * 8 + w) * 2048 + l * 8;
    const _Float16* w2b = W2f + (size_t)(s * 8 + w) * 2048 + l * 8;
#pragma unroll
    for (int kt = 0; kt < 4; ++kt) {
      W1r[kt] = *(const f16x8*)&w1b[kt * 512];
      W2r[kt] = *(const f16x8*)&w2b[kt * 512];
    }
  }

  const int hd = w * 16 + (l & 15);
  const float Vhd = V[s * 128 + hd];
  const float b12 = b1[s * 128 + hd] + b2[s * 128 + hd];
  const int kc = (l >> 4) << 3;

  {
    const int rsrc = min(l & 15, 7);
    f32x4 dm = (f32x4){0.f, 0.f, 0.f, 0.f};
#pragma unroll
    for (int kt = 0; kt < 4; ++kt) {
      const float* hp = hn + (size_t)(nbase + rsrc) * 128 + kt * 32 + kc;
      const float4 a = *(const float4*)(hp);
      const float4 b = *(const float4*)(hp + 4);
      f16x8 ah;
      ah[0]=(_Float16)a.x; ah[1]=(_Float16)a.y; ah[2]=(_Float16)a.z; ah[3]=(_Float16)a.w;
      ah[4]=(_Float16)b.x; ah[5]=(_Float16)b.y; ah[6]=(_Float16)b.z; ah[7]=(_Float16)b.w;
      dm = __builtin_amdgcn_mfma_f32_16x16x32_f16(ah, W1r[kt], dm, 0, 0, 0);
    }
#pragma unroll
    for (int q = 0; q < 4; ++q) u[(l >> 4) * 4 + q][hd] = dm[q] + b12;
  }
  __syncthreads();

#pragma unroll
  for (int m = 0; m < 16; ++m) {
    const int nl = m >> 1, th = m & 1;
    const int cbase = ((nl * 2 + th) * 4) * 64;
    f32x4 acc = (f32x4){0.f, 0.f, 0.f, 0.f};
#pragma unroll
    for (int kt = 0; kt < 4; ++kt) {
      const f16x8 ah = *(const f16x8*)&osh[(cbase + kt * 64 + l) * 8];
      acc = __builtin_amdgcn_mfma_f32_16x16x32_f16(ah, W2r[kt], acc, 0, 0, 0);
    }
    const float uv = u[nl][hd];
#pragma unroll
    for (int q = 0; q < 4; ++q) {
      float p = tanhf_(acc[q] + uv) * Vhd;
      p += __shfl_xor(p, 1);
      p += __shfl_xor(p, 2);
      p += __shfl_xor(p, 4);
      p += __shfl_xor(p, 8);
      const int t = th * 16 + (l >> 4) * 4 + q;
      if ((l & 15) == 0 && t < 30) red[w][nl][t] = p;
    }
  }
  __syncthreads();

  if (tid < 256) {
    const int nl = tid >> 5, t = tid & 31;
    if (t < 30) {
      float sc = 0.f;
#pragma unroll
      for (int ww = 0; ww < 8; ++ww) sc += red[ww][nl][t];
      score[nl][t] = sc;
    }
  }
  __syncthreads();

  {
    const int nl = tid >> 6, jg = tid & 63;
    const int len = lensh[nl];
    float mx = -1e30f;
    for (int t = 0; t < len; ++t) mx = fmaxf(mx, score[nl][t]);
    const float* ob = outs + (size_t)(nbase + nl) * 30 * 128 + jg * 2;
    float sum = 0.f;
    float cx0 = 0.f, cx1 = 0.f;
    for (int t = 0; t < len; ++t) {
      const float e = __expf(score[nl][t] - mx);
      sum += e;
      const float2 o2 = *(const float2*)(ob + (size_t)t * 128);
      cx0 += e * o2.x; cx1 += e * o2.y;
    }
    const float r = rcp_(sum);
    float2 res = {cx0 * r, cx1 * r};
    *(float2*)&ctx[(size_t)(nbase + nl) * 128 + jg * 2] = res;
  }
}

// ---------------------------------------------------------------------------
// K45: FUSED lstm2 + attention2 + output MLP (unchanged).
// ---------------------------------------------------------------------------
__global__ __launch_bounds__(512, 2) void k45_fused(const float* __restrict__ Wih,
                                                    const float* __restrict__ bih,
                                                    const float* __restrict__ Whh,
                                                    const float* __restrict__ bhh,
                                                    const float* __restrict__ aW1,
                                                    const float* __restrict__ ab1,
                                                    const float* __restrict__ aW2,
                                                    const float* __restrict__ ab2,
                                                    const float* __restrict__ aV,
                                                    const float* __restrict__ x1W,
                                                    const float* __restrict__ x1b,
                                                    const float* __restrict__ x2W,
                                                    const float* __restrict__ x2b,
                                                    const float* __restrict__ ctx,
                                                    float* __restrict__ y) {
  const int s = blockIdx.y, b = blockIdx.x;
  const int tid = threadIdx.x;
  __shared__ float xs[5][128];
  __shared__ float hsm[5][128];
  __shared__ float hcur[128];
  __shared__ float gsh[512];
  __shared__ float red[4][128];
  __shared__ float wred[2];
  __shared__ float sc[5];
  __shared__ float u_sh[128];
  __shared__ float cs2[128];
  __shared__ float t1[128];
  __shared__ float red2[8][64];

  for (int idx = tid; idx < 640; idx += 512)
    (&xs[0][0])[idx] = ctx[(size_t)(s * 160 + b * 5) * 128 + idx];
  if (tid < 128) hcur[tid] = 0.f;
  __syncthreads();

  const float* Wis = Wih + (size_t)s * 65536;
  const float* Whs = Whh + (size_t)s * 65536;
  const float bias = bih[s * 512 + tid] + bhh[s * 512 + tid];
  float xw[5] = {bias, bias, bias, bias, bias};
  float whh[128];
#pragma unroll
  for (int k = 0; k < 128; ++k) {
    const float wi = Wis[k * 512 + tid];
    whh[k] = Whs[k * 512 + tid];
#pragma unroll
    for (int dd = 0; dd < 5; ++dd) xw[dd] += xs[dd][k] * wi;
  }

  float c = 0.f;
  for (int dd = 0; dd < 5; ++dd) {
    float g = xw[dd];
#pragma unroll
    for (int k = 0; k < 128; ++k) g += hcur[k] * whh[k];
    gsh[tid] = g;
    __syncthreads();
    if (tid < 128) {
      const int j = tid;
      const float c2 = sigf(gsh[128 + j]) * c + sigf(gsh[j]) * tanhf_(gsh[256 + j]);
      const float h2 = sigf(gsh[384 + j]) * tanhf_(c2);
      c = c2;
      hcur[j] = h2;
      hsm[dd][j] = h2;
    }
    __syncthreads();
  }

  const int q = tid >> 7, j = tid & 127;
  const float* W1s = aW1 + (size_t)s * 16384;
  const float* W2s = aW2 + (size_t)s * 16384;

  {
    float part = 0.f;
#pragma unroll
    for (int k = 0; k < 32; ++k) part += hsm[4][q * 32 + k] * W1s[(q * 32 + k) * 128 + j];
    red[q][j] = part;
  }
  __syncthreads();
  if (tid < 128)
    u_sh[j] = red[0][j] + red[1][j] + red[2][j] + red[3][j] +
              ab1[s * 128 + j] + ab2[s * 128 + j];
  __syncthreads();

  for (int d = 0; d < 5; ++d) {
    float part = 0.f;
#pragma unroll
    for (int k = 0; k < 32; ++k) part += hsm[d][q * 32 + k] * W2s[(q * 32 + k) * 128 + j];
    red[q][j] = part;
    __syncthreads();
    if (tid < 128) {
      float a = u_sh[j] + red[0][j] + red[1][j] + red[2][j] + red[3][j];
      float pv = tanhf_(a) * aV[s * 128 + j];
#pragma unroll
      for (int off = 32; off; off >>= 1) pv += __shfl_down(pv, off);
      if ((tid & 63) == 0) wred[tid >> 6] = pv;
    }
    __syncthreads();
    if (tid == 0) sc[d] = wred[0] + wred[1];
    __syncthreads();
  }

  if (tid < 128) {
    float m = sc[0];
#pragma unroll
    for (int d = 1; d < 5; ++d) m = fmaxf(m, sc[d]);
    float e[5], sum = 0.f;
#pragma unroll
    for (int d = 0; d < 5; ++d) { e[d] = __expf(sc[d] - m); sum += e[d]; }
    float cx = 0.f;
#pragma unroll
    for (int d = 0; d < 5; ++d) cx += e[d] * hsm[d][j];
    cs2[j] = cx * rcp_(sum);
  }
  __syncthreads();

  {
    float part = 0.f;
#pragma unroll
    for (int k = 0; k < 32; ++k) part += cs2[q * 32 + k] * x1W[(size_t)s * 16384 + (q * 32 + k) * 128 + j];
    red[q][j] = part;
  }
  __syncthreads();
  if (tid < 128)
    t1[j] = fmaxf(red[0][j] + red[1][j] + red[2][j] + red[3][j] + x1b[s * 128 + j], 0.f);
  __syncthreads();

  {
    const int q2 = tid >> 6, j2 = tid & 63;
    float part = 0.f;
#pragma unroll
    for (int k = 0; k < 16; ++k) part += t1[q2 * 16 + k] * x2W[(size_t)s * 8192 + (q2 * 16 + k) * 64 + j2];
    red2[q2][j2] = part;
  }
  __syncthreads();
  if (tid < 64) {
    float yy = x2b[s * 64 + tid];
#pragma unroll
    for (int g = 0; g < 8; ++g) yy += red2[g][tid];
    y[(size_t)(s * 32 + b) * 64 + tid] = yy;
  }
}

// ---------------------------------------------------------------------------
// K6: final combine (unchanged).
// ---------------------------------------------------------------------------
__global__ __launch_bounds__(256) void k6_final(const float* __restrict__ stock,
                                                const float* __restrict__ h1W,
                                                const float* __restrict__ h1b,
                                                const float* __restrict__ h2W,
                                                const float* __restrict__ h2b,
                                                const float* __restrict__ hcW,
                                                const float* __restrict__ hcb,
                                                const float* __restrict__ yws,
                                                float* __restrict__ out) {
  const int tid = threadIdx.x;
  __shared__ float sf[32 * 17];
  __shared__ float hid[32 * 64];
  __shared__ float xs[32 * 32];
  for (int idx = tid; idx < 544; idx += 256) sf[idx] = stock[idx];
  __syncthreads();
  for (int idx = tid; idx < 2048; idx += 256) {
    const int b = idx >> 6, k = idx & 63;
    float a = h1b[k];
    for (int q = 0; q < 17; ++q) a += sf[b * 17 + q] * h1W[q * 64 + k];
    hid[idx] = fmaxf(a, 0.f);
  }
  __syncthreads();
  for (int idx = tid; idx < 1024; idx += 256) {
    const int b = idx >> 5, mm = idx & 31;
    float a = h2b[mm];
    for (int k = 0; k < 64; ++k) a += hid[b * 64 + k] * h2W[k * 32 + mm];
    xs[idx] = a;
  }
  __syncthreads();
  {
    const int b = tid >> 3, o = tid & 7;
    float a = hcb[o];
    for (int c = 0; c < 32; ++c) a += xs[b * 32 + c] * hcW[c * 8 + o];
    for (int c = 32; c < 544; ++c) {
      const int ss = (c - 32) >> 6, k = (c - 32) & 63;
      a += yws[((size_t)ss * 32 + b) * 64 + k] * hcW[c * 8 + o];
    }
    out[tid] = tanhf_(a);
  }
}

// ---------------------------------------------------------------------------
extern "C" void kernel_launch(void* const* d_in, const int* in_sizes, int n_in,
                              void* d_out, int out_size, void* d_ws, size_t ws_size,
                              hipStream_t stream) {
  (void)in_sizes; (void)n_in; (void)out_size; (void)ws_size;
  const float* stock = (const float*)d_in[0];
  const float* sent  = (const float*)d_in[1];
  const float* times = (const float*)d_in[2];
  const int*   lens  = (const int*)d_in[3];
  const float* tlWall = (const float*)d_in[4];
  const float* tlball = (const float*)d_in[5];
  const float* tlUall = (const float*)d_in[6];
  const float* tlbU   = (const float*)d_in[7];
  const float* tlWd   = (const float*)d_in[8];
  const float* tlbd   = (const float*)d_in[9];
  const float* a1W1 = (const float*)d_in[10];
  const float* a1b1 = (const float*)d_in[11];
  const float* a1W2 = (const float*)d_in[12];
  const float* a1b2 = (const float*)d_in[13];
  const float* a1V  = (const float*)d_in[14];
  const float* a1bV = (const float*)d_in[15];
  const float* l2Wih = (const float*)d_in[16];
  const float* l2bih = (const float*)d_in[17];
  const float* l2Whh = (const float*)d_in[18];
  const float* l2bhh = (const float*)d_in[19];
  const float* a2W1 = (const float*)d_in[20];
  const float* a2b1 = (const float*)d_in[21];
  const float* a2W2 = (const float*)d_in[22];
  const float* a2b2 = (const float*)d_in[23];
  const float* a2V  = (const float*)d_in[24];
  const float* a2bV = (const float*)d_in[25];
  const float* x1W  = (const float*)d_in[26];
  const float* x1b  = (const float*)d_in[27];
  const float* x2W  = (const float*)d_in[28];
  const float* x2b  = (const float*)d_in[29];
  const float* h1W  = (const float*)d_in[30];
  const float* h1b  = (const float*)d_in[31];
  const float* h2W  = (const float*)d_in[32];
  const float* h2b  = (const float*)d_in[33];
  const float* hcW  = (const float*)d_in[34];
  const float* hcb  = (const float*)d_in[35];
  (void)a1bV; (void)a2bV;

  float* ws = (float*)d_ws;
  float* XU    = ws;               // 8*160*30*512   = 19,660,800
  float* outs  = XU + 19660800;    // 8*160*30*128   =  4,915,200
  float* hnb   = outs + 4915200;   // 8*160*128      =    163,840
  float* ctx   = hnb + 163840;     // 8*160*128      =    163,840
  float* yb    = ctx + 163840;     // 8*32*64        =     16,384
  _Float16* Uhw = (_Float16*)(yb + 16384);    // 8*512*768 halfs
  _Float16* Wfh = Uhw + 8 * 512 * 768;        // 8*8*8192 halfs
  _Float16* Dfh = Wfh + 8 * 8 * 8192;         // 8*8*2048 halfs
  _Float16* W1f = Dfh + 8 * 8 * 2048;         // 8*8*2048 halfs
  _Float16* W2f = W1f + 8 * 8 * 2048;         // 8*8*2048 halfs
  int* rowmap = (int*)(W2f + 8 * 8 * 2048);   // 8*4800 ints
  int* Msd    = rowmap + 8 * 4800;            // 8 ints

  k0_rowmap<<<8, 256, 0, stream>>>(lens, rowmap, Msd);
  k0_usplit<<<dim3(12, 8, 8), 256, 0, stream>>>(tlUall, Uhw);
  k0_wprep<<<dim3(8, 8), 256, 0, stream>>>(tlWall, tlWd, Wfh, Dfh);
  k0_aprep<<<dim3(8, 8), 256, 0, stream>>>(a1W1, a1W2, W1f, W2f);
  k1_xu<<<dim3(8, 300), 256, 0, stream>>>(sent, Uhw, tlbU, rowmap, Msd, XU);
  k2_tlstm<<<dim3(8, 10), 512, 0, stream>>>(Wfh, Dfh, tlball, tlbd, XU, times, lens, outs, hnb);
  k3_attn1<<<dim3(8, 20), 512, 0, stream>>>(W1f, W2f, a1b1, a1b2, a1V, outs, hnb, lens, ctx);
  k45_fused<<<dim3(32, 8), 512, 0, stream>>>(l2Wih, l2bih, l2Whh, l2bhh,
                                             a2W1, a2b1, a2W2, a2b2, a2V,
                                             x1W, x1b, x2W, x2b, ctx, yb);
  k6_final<<<1, 256, 0, stream>>>(stock, h1W, h1b, h2W, h2b, hcW, hcb, yb, (float*)d_out);
}